// Round 6
// baseline (844.644 us; speedup 1.0000x reference)
//
#include <hip/hip_runtime.h>
#include <math.h>

// ---------------- constants ----------------
#define FH 200
#define FW 200
#define HW 40000            // FH*FW
#define NUM_A 9
#define NANCH 360000        // HW*NUM_A
#define PRE_K 2000
#define OUT_K 1000
#define IMG_SZ 1600.0f
#define MIN_SZ 16.0f
#define NMS_TH 0.7f
#define BBOX_CLIP_F 4.135166556742356f   // log(1000/16)

// ---------------- workspace layout (bytes), total ~80.1 MB ----------------
#define OFF_HIST   ((size_t)0)           // 256 u32 = 1024
#define OFF_STATE  ((size_t)1024)        // 16 u32 = 64 (incl tickets [8..11])
#define OFF_CAND   ((size_t)1088)        // 4096 u64 = 32768
#define OFF_BOXS   ((size_t)33856)       // 2000*4 f = 32000
#define OFF_SCS    ((size_t)65856)       // 2000 f = 8000
#define OFF_MASK   ((size_t)73856)       // 2000*32 u64 = 512000
#define OFF_DIAG   ((size_t)585856)      // 2048 u64 = 16384
#define OFF_AWH    ((size_t)602240)      // 73728*16 = 1179648
#define OFF_AWM    ((size_t)1781888)
#define OFF_AWL    ((size_t)2961536)
#define OFF_HWH    ((size_t)4141184)     // 1536*16 = 24576
#define OFF_HWM    ((size_t)4165760)
#define OFF_HWL    ((size_t)4190336)
#define OFF_LOGIT  ((size_t)4214912)     // 40000*45*4 = 7,200,000 (single buf now)
#define OFF_PH     ((size_t)18614912)    // 8*40000*32*2 = 20,480,000
#define OFF_PM     ((size_t)39094912)
#define OFF_PL     ((size_t)59574912)    // end 80,054,912
#define OFF_PROP   ((size_t)18614912)    // alias PH (planes dead after conv)
#define OFF_SCORE  ((size_t)24374912)    // alias PH

typedef __attribute__((ext_vector_type(8))) short short8;
typedef __attribute__((ext_vector_type(4))) float floatx4;
#define MFMA16(a, b, c) __builtin_amdgcn_mfma_f32_16x16x32_bf16(a, b, c, 0, 0, 0)

__device__ __forceinline__ unsigned short rne_bf16(float v) {
  unsigned int bb = __float_as_uint(v);
  return (unsigned short)((bb + 0x7FFFu + ((bb >> 16) & 1u)) >> 16);
}

// 3-way split: v = h + m + l + eps, |eps| <~ 2^-25 |v|
__device__ __forceinline__ void split3(float v, unsigned short& h,
                                       unsigned short& m, unsigned short& l) {
  h = rne_bf16(v);
  float r1 = v - __uint_as_float(((unsigned int)h) << 16);
  m = rne_bf16(r1);
  float r2 = r1 - __uint_as_float(((unsigned int)m) << 16);
  l = rne_bf16(r2);
}

// =====================================================================
// Fused prepass (one launch):
//   blocks [0,1256): split3 feat into 3 bf16 planes, layout [cib][px][32ci]
//   blocks [1256,1550): swizzle conv + head weights into MFMA A-fragment
//     order, 3-way split.
// =====================================================================
__global__ __launch_bounds__(256) void prep_all(
    const float* __restrict__ feat, const float* __restrict__ w,
    const float* __restrict__ cls_w, const float* __restrict__ reg_w,
    unsigned short* __restrict__ Ph, unsigned short* __restrict__ Pm,
    unsigned short* __restrict__ Pl, uint4* __restrict__ AW_h,
    uint4* __restrict__ AW_m, uint4* __restrict__ AW_l,
    uint4* __restrict__ HwF_h, uint4* __restrict__ HwF_m,
    uint4* __restrict__ HwF_l) {
  int bx = blockIdx.x;
  int t = threadIdx.x;
  if (bx < 1256) {
    int cib = bx & 7;
    int px = (bx >> 3) * 256 + t;
    if (px >= HW) return;
    unsigned short h[32], m[32], l[32];
#pragma unroll
    for (int ci = 0; ci < 32; ++ci)
      split3(feat[(size_t)(cib * 32 + ci) * HW + px], h[ci], m[ci], l[ci]);
    size_t base = ((size_t)cib * HW + px) * 32;
    uint4* dh = (uint4*)(Ph + base);
    uint4* dm = (uint4*)(Pm + base);
    uint4* dl = (uint4*)(Pl + base);
#pragma unroll
    for (int k = 0; k < 4; ++k) {
      uint4 vh, vm, vl;
      vh.x = h[k * 8 + 0] | (h[k * 8 + 1] << 16);
      vh.y = h[k * 8 + 2] | (h[k * 8 + 3] << 16);
      vh.z = h[k * 8 + 4] | (h[k * 8 + 5] << 16);
      vh.w = h[k * 8 + 6] | (h[k * 8 + 7] << 16);
      vm.x = m[k * 8 + 0] | (m[k * 8 + 1] << 16);
      vm.y = m[k * 8 + 2] | (m[k * 8 + 3] << 16);
      vm.z = m[k * 8 + 4] | (m[k * 8 + 5] << 16);
      vm.w = m[k * 8 + 6] | (m[k * 8 + 7] << 16);
      vl.x = l[k * 8 + 0] | (l[k * 8 + 1] << 16);
      vl.y = l[k * 8 + 2] | (l[k * 8 + 3] << 16);
      vl.z = l[k * 8 + 4] | (l[k * 8 + 5] << 16);
      vl.w = l[k * 8 + 6] | (l[k * 8 + 7] << 16);
      dh[k] = vh; dm[k] = vm; dl[k] = vl;
    }
    return;
  }
  int gid = (bx - 1256) * 256 + t;
  unsigned short h[8], m[8], l[8];
  if (gid < 73728) {
    int L = gid & 63;
    int idx = gid >> 6;            // (ctg*9+tap)*8 + cib
    int cib = idx & 7;
    int tmp = idx >> 3;
    int tap = tmp % 9;
    int ctg = tmp / 9;
    int co = ctg * 16 + (L & 15);
    int ci0 = cib * 32 + (L >> 4) * 8;
#pragma unroll
    for (int j = 0; j < 8; ++j)
      split3(w[(size_t)co * 2304 + (ci0 + j) * 9 + tap], h[j], m[j], l[j]);
    uint4 vh, vm, vl;
    vh.x = h[0] | (h[1] << 16); vh.y = h[2] | (h[3] << 16);
    vh.z = h[4] | (h[5] << 16); vh.w = h[6] | (h[7] << 16);
    vm.x = m[0] | (m[1] << 16); vm.y = m[2] | (m[3] << 16);
    vm.z = m[4] | (m[5] << 16); vm.w = m[6] | (m[7] << 16);
    vl.x = l[0] | (l[1] << 16); vl.y = l[2] | (l[3] << 16);
    vl.z = l[4] | (l[5] << 16); vl.w = l[6] | (l[7] << 16);
    AW_h[gid] = vh; AW_m[gid] = vm; AW_l[gid] = vl;
  } else if (gid < 73728 + 1536) {
    int g2 = gid - 73728;
    int L = g2 & 63;
    int idx = g2 >> 6;             // mt*8 + kb
    int kb = idx & 7;
    int mt = idx >> 3;
    int mm = mt * 16 + (L & 15);
    int co0 = kb * 32 + (L >> 4) * 8;
#pragma unroll
    for (int j = 0; j < 8; ++j) {
      float v = 0.f;
      if (mm < 9) v = cls_w[mm * 256 + co0 + j];
      else if (mm < 45) v = reg_w[(mm - 9) * 256 + co0 + j];
      split3(v, h[j], m[j], l[j]);
    }
    uint4 vh, vm, vl;
    vh.x = h[0] | (h[1] << 16); vh.y = h[2] | (h[3] << 16);
    vh.z = h[4] | (h[5] << 16); vh.w = h[6] | (h[7] << 16);
    vm.x = m[0] | (m[1] << 16); vm.y = m[2] | (m[3] << 16);
    vm.z = m[4] | (m[5] << 16); vm.w = m[6] | (m[7] << 16);
    vl.x = l[0] | (l[1] << 16); vl.y = l[2] | (l[3] << 16);
    vl.z = l[4] | (l[5] << 16); vl.w = l[6] | (l[7] << 16);
    HwF_h[g2] = vh; HwF_m[g2] = vm; HwF_l[g2] = vl;
  }
}

// =====================================================================
// Main conv+heads MFMA kernel — RETILED: block = 4 px-rows x 16 px-cols
// x ALL 256 co. 4 waves, each wave 4 ctg (64 co) x 4 r. Grid 13x50=650.
// vs previous 128co-half tiling: B-LDS-reads per MFMA halved (ct=4),
// feat staged once (not twice), logits single-buffer (written once).
// Accumulator chains receive the identical MFMA sequences as before
// (same cib/tap/6-product order; head sums added haA+haB exactly as
// finalize's lpA+lpB was) => bit-identical output.
// Staging tile: [6 rows][18 cols][40 u16-pad] x3 planes = 25,920 B.
// Epilogue tile: [64 px][136 co-pad] x3 = 52,224 B (two co-half passes).
// T14 prefetch removed (measured null in R5).
// =====================================================================
__global__ __launch_bounds__(256, 3) void conv_mfma(
    const unsigned short* __restrict__ Ph, const unsigned short* __restrict__ Pm,
    const unsigned short* __restrict__ Pl, const uint4* __restrict__ AW_h,
    const uint4* __restrict__ AW_m, const uint4* __restrict__ AW_l,
    const uint4* __restrict__ HwF_h, const uint4* __restrict__ HwF_m,
    const uint4* __restrict__ HwF_l, const float* __restrict__ bias,
    float* __restrict__ logits) {
  __shared__ alignas(16) unsigned short smem[26112];  // 52,224 B
  const int t = threadIdx.x;
  const int L = t & 63, wv = t >> 6;
  const int q = L >> 4, nl = L & 15;
  const int w0 = blockIdx.x * 16;
  const int h0 = blockIdx.y * 4;

  floatx4 acc[4][4];
#pragma unroll
  for (int ct = 0; ct < 4; ++ct)
#pragma unroll
    for (int r = 0; r < 4; ++r) acc[ct][r] = (floatx4)0.f;

  unsigned short* flh = smem;            // [6 rows][18 cols][40 u16-pad]
  unsigned short* flm = smem + 4320;
  unsigned short* fll = smem + 8640;

  for (int cib = 0; cib < 8; ++cib) {
    __syncthreads();
    // ---- stage: 432 16B-chunks per plane (6 rows x 18 cols x 4) ----
#pragma unroll
    for (int j = 0; j < 6; ++j) {
      const int p = j >> 1;              // plane (static after unroll)
      const int c = (j & 1) * 256 + t;   // chunk id in [0,512)
      if (c < 432) {
        int rr = (int)((unsigned)c / 72u);
        int rem = c - rr * 72;
        int cc = rem >> 2, q16 = rem & 3;
        int gr = h0 - 1 + rr, gc = w0 - 1 + cc;
        uint4 v; v.x = v.y = v.z = v.w = 0u;
        if ((unsigned)gr < (unsigned)FH && (unsigned)gc < (unsigned)FW) {
          const unsigned short* pp = (p == 0) ? Ph : (p == 1) ? Pm : Pl;
          v = *(const uint4*)(pp +
                ((size_t)(cib * HW + gr * FW + gc) * 32 + q16 * 8));
        }
        *(uint4*)(smem + p * 4320 + rr * 720 + cc * 40 + q16 * 8) = v;
      }
    }
    __syncthreads();
    __builtin_amdgcn_s_setprio(1);
    for (int kh = 0; kh < 3; ++kh) {
      for (int kw = 0; kw < 3; ++kw) {
        const int tap = kh * 3 + kw;
        short8 ah[4], am[4], al[4];
#pragma unroll
        for (int ct = 0; ct < 4; ++ct) {
          const int ab = (((wv * 4 + ct) * 9 + tap) * 8 + cib) * 64 + L;
          ah[ct] = ((const short8*)AW_h)[ab];
          am[ct] = ((const short8*)AW_m)[ab];
          al[ct] = ((const short8*)AW_l)[ab];
        }
        const int cbase = (nl + kw) * 40 + q * 8;
#pragma unroll
        for (int r = 0; r < 4; ++r) {
          const int off = (r + kh) * 720 + cbase;
          short8 bh = *(const short8*)(flh + off);
          short8 bm = *(const short8*)(flm + off);
          short8 bl = *(const short8*)(fll + off);
#pragma unroll
          for (int ct = 0; ct < 4; ++ct) {
            acc[ct][r] = MFMA16(ah[ct], bh, acc[ct][r]);
            acc[ct][r] = MFMA16(ah[ct], bm, acc[ct][r]);
            acc[ct][r] = MFMA16(am[ct], bh, acc[ct][r]);
            acc[ct][r] = MFMA16(ah[ct], bl, acc[ct][r]);
            acc[ct][r] = MFMA16(am[ct], bm, acc[ct][r]);
            acc[ct][r] = MFMA16(al[ct], bh, acc[ct][r]);
          }
        }
      }
    }
    __builtin_amdgcn_s_setprio(0);
  }

  // ---- epilogue: two co-half passes (ch=0: co 0-127, ch=1: co 128-255) ----
  float bv[4][4];
#pragma unroll
  for (int ct = 0; ct < 4; ++ct)
#pragma unroll
    for (int i = 0; i < 4; ++i)
      bv[ct][i] = bias[(wv * 4 + ct) * 16 + q * 4 + i];

  unsigned short* xlh = smem;           // [64 px][136 co-pad] u16
  unsigned short* xlm = smem + 8704;
  unsigned short* xll = smem + 17408;

  floatx4 ha[2][3];
#pragma unroll
  for (int ch = 0; ch < 2; ++ch)
#pragma unroll
    for (int mt = 0; mt < 3; ++mt) ha[ch][mt] = (floatx4)0.f;

#pragma unroll
  for (int ch = 0; ch < 2; ++ch) {
    __syncthreads();                    // prior readers of smem done
    if ((wv >> 1) == ch) {
      const int u = wv & 1;             // 0..1 within this co-half
#pragma unroll
      for (int ct = 0; ct < 4; ++ct) {
#pragma unroll
        for (int r = 0; r < 4; ++r) {
          unsigned short xh[4], xm[4], xl_[4];
#pragma unroll
          for (int i = 0; i < 4; ++i) {
            float xv = fmaxf(acc[ct][r][i] + bv[ct][i], 0.f);
            split3(xv, xh[i], xm[i], xl_[i]);
          }
          int px_l = r * 16 + nl;
          int co_l = (u * 4 + ct) * 16 + q * 4;
          uint2 ph, pm, pl;
          ph.x = xh[0] | (xh[1] << 16); ph.y = xh[2] | (xh[3] << 16);
          pm.x = xm[0] | (xm[1] << 16); pm.y = xm[2] | (xm[3] << 16);
          pl.x = xl_[0] | (xl_[1] << 16); pl.y = xl_[2] | (xl_[3] << 16);
          *(uint2*)(xlh + px_l * 136 + co_l) = ph;
          *(uint2*)(xlm + px_l * 136 + co_l) = pm;
          *(uint2*)(xll + px_l * 136 + co_l) = pl;
        }
      }
    }
    __syncthreads();
    for (int ks = 0; ks < 4; ++ks) {
      const int off = (wv * 16 + nl) * 136 + ks * 32 + q * 8;
      short8 bh = *(const short8*)(xlh + off);
      short8 bm = *(const short8*)(xlm + off);
      short8 bl = *(const short8*)(xll + off);
#pragma unroll
      for (int mt = 0; mt < 3; ++mt) {
        const int hb = (mt * 8 + ch * 4 + ks) * 64 + L;
        short8 hh = ((const short8*)HwF_h)[hb];
        short8 hm = ((const short8*)HwF_m)[hb];
        short8 hl = ((const short8*)HwF_l)[hb];
        ha[ch][mt] = MFMA16(hh, bh, ha[ch][mt]);
        ha[ch][mt] = MFMA16(hh, bm, ha[ch][mt]);
        ha[ch][mt] = MFMA16(hm, bh, ha[ch][mt]);
        ha[ch][mt] = MFMA16(hh, bl, ha[ch][mt]);
        ha[ch][mt] = MFMA16(hm, bm, ha[ch][mt]);
        ha[ch][mt] = MFMA16(hl, bh, ha[ch][mt]);
      }
    }
  }

  int gr = h0 + wv;
  int gc = w0 + nl;
  if (gc < FW) {
    float* lp = logits + (size_t)(gr * FW + gc) * 45;
#pragma unroll
    for (int mt = 0; mt < 3; ++mt)
#pragma unroll
      for (int i = 0; i < 4; ++i) {
        int head = mt * 16 + q * 4 + i;
        if (head < 45) lp[head] = ha[0][mt][i] + ha[1][mt][i];
      }
  }
}

// =====================================================================
// finalize — bias + anchors + deltas + sigmoid from (single) logits.
// Fused radix hist pass-0 AND scan-0 (last-block ticket).
// =====================================================================
__global__ __launch_bounds__(256) void finalize_kernel(
    const float* __restrict__ logits, const float* __restrict__ cls_b,
    const float* __restrict__ reg_b, float* __restrict__ prop,
    float* __restrict__ score, unsigned int* __restrict__ hist,
    unsigned int* __restrict__ state) {
  __shared__ unsigned int hsh[256], s1[256];
  __shared__ int lastb;
  int t = threadIdx.x;
  hsh[t] = 0u;
  __syncthreads();
  int px = blockIdx.x * 256 + t;
  if (px < HW) {
    float A[45];
    const float* lp = logits + (size_t)px * 45;
#pragma unroll
    for (int i = 0; i < 45; ++i) A[i] = lp[i];
    const float scv[3] = {128.f, 256.f, 512.f};
    const float arv[3] = {0.5f, 1.f, 2.f};
    float sx = (float)(px % FW) * 8.0f;
    float sy = (float)(px / FW) * 8.0f;
#pragma unroll
    for (int a = 0; a < NUM_A; ++a) {
      int ai = a / 3, si = a % 3;
      float hr = sqrtf(arv[ai]);
      float wr = 1.0f / hr;
      float rw = nearbyintf(wr * scv[si] * 0.5f);
      float rh = nearbyintf(hr * scv[si] * 0.5f);
      float ax0 = sx - rw, ay0 = sy - rh, ax1 = sx + rw, ay1 = sy + rh;
      float aw = ax1 - ax0, ah = ay1 - ay0;
      float cx = ax0 + 0.5f * aw, cy = ay0 + 0.5f * ah;
      float dx = A[9 + a * 4 + 0] + reg_b[a * 4 + 0];
      float dy = A[9 + a * 4 + 1] + reg_b[a * 4 + 1];
      float dw = fminf(A[9 + a * 4 + 2] + reg_b[a * 4 + 2], BBOX_CLIP_F);
      float dh = fminf(A[9 + a * 4 + 3] + reg_b[a * 4 + 3], BBOX_CLIP_F);
      float pcx = dx * aw + cx;
      float pcy = dy * ah + cy;
      float pw = expf(dw) * aw;
      float ph = expf(dh) * ah;
      size_t base = (size_t)(px * NUM_A + a) * 4;
      prop[base + 0] = pcx - 0.5f * pw;
      prop[base + 1] = pcy - 0.5f * ph;
      prop[base + 2] = pcx + 0.5f * pw;
      prop[base + 3] = pcy + 0.5f * ph;
      float lg = A[a] + cls_b[a];
      float sv = 1.0f / (1.0f + expf(-lg));
      score[px * NUM_A + a] = sv;
      atomicAdd(&hsh[__float_as_uint(sv) >> 24], 1u);
    }
  }
  __syncthreads();
  if (hsh[t]) atomicAdd(&hist[t], hsh[t]);
  __syncthreads();
  if (t == 0) lastb = (atomicAdd(&state[8], 1u) == gridDim.x - 1u) ? 1 : 0;
  __syncthreads();
  if (!lastb) return;
  __threadfence();
  // ---- scan pass 0 ----
  unsigned int hv = hist[t];
  hist[t] = 0u;
  hsh[t] = hv;
  __syncthreads();
  unsigned int* A = hsh;
  unsigned int* B = s1;
  for (int off = 1; off < 256; off <<= 1) {
    B[t] = A[t] + ((t + off < 256) ? A[t + off] : 0u);
    __syncthreads();
    unsigned int* tmp = A; A = B; B = tmp;
  }
  unsigned int rem = (unsigned)PRE_K;
  unsigned int suf = A[t];
  unsigned int sufn = (t < 255) ? A[t + 1] : 0u;
  if (suf >= rem && sufn < rem) {
    state[0] = (unsigned int)t;
    state[1] = rem - sufn;
  }
}

// =====================================================================
// Radix passes 1..3: histogram + fused last-block scan (ticket).
// =====================================================================
__global__ __launch_bounds__(256) void hist_scan_kernel(
    const float* __restrict__ score, unsigned int* __restrict__ hist,
    unsigned int* __restrict__ state, unsigned int* __restrict__ ticket,
    int pass) {
  __shared__ unsigned int h[256], s1[256];
  __shared__ int lastb;
  int t = threadIdx.x;
  h[t] = 0;
  __syncthreads();
  unsigned int prefix = state[0];
  int shift = 24 - 8 * pass;
  for (int i = blockIdx.x * 256 + t; i < NANCH; i += gridDim.x * 256) {
    unsigned int key = __float_as_uint(score[i]);
    if ((key >> (32 - 8 * pass)) == prefix)
      atomicAdd(&h[(key >> shift) & 255u], 1u);
  }
  __syncthreads();
  if (h[t]) atomicAdd(&hist[t], h[t]);
  __syncthreads();
  if (t == 0) lastb = (atomicAdd(ticket, 1u) == gridDim.x - 1u) ? 1 : 0;
  __syncthreads();
  if (!lastb) return;
  __threadfence();
  unsigned int hv = hist[t];
  hist[t] = 0u;
  h[t] = hv;
  __syncthreads();
  unsigned int* A = h;
  unsigned int* B = s1;
  for (int off = 1; off < 256; off <<= 1) {
    B[t] = A[t] + ((t + off < 256) ? A[t + off] : 0u);
    __syncthreads();
    unsigned int* tmp = A; A = B; B = tmp;
  }
  unsigned int rem = state[1];
  unsigned int suf = A[t];
  unsigned int sufn = (t < 255) ? A[t + 1] : 0u;
  if (suf >= rem && sufn < rem) {
    state[0] = (prefix << 8) | (unsigned int)t;
    state[1] = rem - sufn;
  }
}

__global__ __launch_bounds__(256) void collect_kernel(
    const float* __restrict__ score, unsigned int* __restrict__ state,
    unsigned long long* __restrict__ cand) {
  unsigned int T = state[0];
  for (int i = blockIdx.x * 256 + threadIdx.x; i < NANCH; i += gridDim.x * 256) {
    unsigned int key = __float_as_uint(score[i]);
    if (key >= T) {
      unsigned int pos = atomicAdd(&state[4], 1u);
      if (pos < 4096u)
        cand[pos] = ((unsigned long long)key << 32) |
                    (unsigned long long)(~(unsigned int)i);
    }
  }
}

// =====================================================================
// Bitonic sort + gather + clip + valid + stable partition
// =====================================================================
__global__ __launch_bounds__(1024) void sort_gather(
    const unsigned long long* __restrict__ cand,
    const unsigned int* __restrict__ state, const float* __restrict__ prop,
    const float* __restrict__ score, float* __restrict__ boxes_s,
    float* __restrict__ sc_s) {
  __shared__ unsigned long long sk[4096];
  int t = threadIdx.x;
  unsigned int cnt = state[4];
  if (cnt > 4096u) cnt = 4096u;
  for (int e = t; e < 4096; e += 1024) sk[e] = (e < (int)cnt) ? cand[e] : 0ull;
  __syncthreads();
  for (int k = 2; k <= 4096; k <<= 1) {
    for (int j = k >> 1; j > 0; j >>= 1) {
      for (int i = t; i < 4096; i += 1024) {
        int l = i ^ j;
        if (l > i) {
          unsigned long long a = sk[i], bb = sk[l];
          bool up = ((i & k) == 0);
          bool sw = up ? (a < bb) : (a > bb);
          if (sw) { sk[i] = bb; sk[l] = a; }
        }
      }
      __syncthreads();
    }
  }
  float bx[2][4];
  float sc2[2] = {-1.f, -1.f};
  bool valid2[2] = {false, false};
#pragma unroll
  for (int s = 0; s < 2; ++s) {
    int i = t + s * 1024;
    bx[s][0] = bx[s][1] = bx[s][2] = bx[s][3] = 0.f;
    if (i < PRE_K) {
      unsigned long long v = sk[i];
      unsigned int idx = ~(unsigned int)(v & 0xFFFFFFFFull);
      float4 p = *(const float4*)(prop + (size_t)idx * 4);
      float x0 = fminf(fmaxf(p.x, 0.f), IMG_SZ);
      float y0 = fminf(fmaxf(p.y, 0.f), IMG_SZ);
      float x1 = fminf(fmaxf(p.z, 0.f), IMG_SZ);
      float y1 = fminf(fmaxf(p.w, 0.f), IMG_SZ);
      bool valid = (x1 - x0 >= MIN_SZ) && (y1 - y0 >= MIN_SZ);
      bx[s][0] = x0; bx[s][1] = y0; bx[s][2] = x1; bx[s][3] = y1;
      valid2[s] = valid;
      sc2[s] = valid ? score[idx] : -1.0f;
    }
  }
  __syncthreads();
  int* A = (int*)sk;
  int* B = A + 2048;
#pragma unroll
  for (int s = 0; s < 2; ++s) {
    int i = t + s * 1024;
    A[i] = (i < PRE_K && valid2[s]) ? 1 : 0;
  }
  __syncthreads();
  for (int off = 1; off < 2048; off <<= 1) {
#pragma unroll
    for (int s = 0; s < 2; ++s) {
      int i = t + s * 1024;
      B[i] = A[i] + ((i >= off) ? A[i - off] : 0);
    }
    __syncthreads();
    int* tmp = A; A = B; B = tmp;
  }
  int total = A[2047];
#pragma unroll
  for (int s = 0; s < 2; ++s) {
    int i = t + s * 1024;
    if (i < PRE_K) {
      int inc = A[i];
      int pos = valid2[s] ? (inc - 1) : (total + (i - inc));
      boxes_s[pos * 4 + 0] = bx[s][0];
      boxes_s[pos * 4 + 1] = bx[s][1];
      boxes_s[pos * 4 + 2] = bx[s][2];
      boxes_s[pos * 4 + 3] = bx[s][3];
      sc_s[pos] = sc2[s];
    }
  }
}

// =====================================================================
// IoU suppression bitmask (+ coalesced diag words)
// =====================================================================
__global__ __launch_bounds__(64) void iou_kernel(
    const float* __restrict__ boxes_s, unsigned long long* __restrict__ mask,
    unsigned long long* __restrict__ diag) {
  int bi = blockIdx.y, bj = blockIdx.x;
  int t = threadIdx.x;
  __shared__ float4 cb[64];
  int jc = bj * 64 + t;
  float4 z; z.x = z.y = z.z = z.w = 0.f;
  cb[t] = (jc < PRE_K) ? *(const float4*)(boxes_s + (size_t)jc * 4) : z;
  __syncthreads();
  int i = bi * 64 + t;
  if (i >= PRE_K) return;
  float4 a = *(const float4*)(boxes_s + (size_t)i * 4);
  float areaA = (a.z - a.x) * (a.w - a.y);
  unsigned long long bits = 0ull;
  for (int jj = 0; jj < 64; ++jj) {
    int j = bj * 64 + jj;
    if (j < PRE_K && j > i) {
      float4 b = cb[jj];
      float areaB = (b.z - b.x) * (b.w - b.y);
      float ltx = fmaxf(a.x, b.x), lty = fmaxf(a.y, b.y);
      float rbx = fminf(a.z, b.z), rby = fminf(a.w, b.w);
      float w = fmaxf(rbx - ltx, 0.f), h = fmaxf(rby - lty, 0.f);
      float inter = w * h;
      float iou = inter / (areaA + areaB - inter + 1e-9f);
      if (iou > NMS_TH) bits |= (1ull << jj);
    }
  }
  mask[(size_t)i * 32 + bj] = bits;
  if (bi == bj) diag[i] = bits;
}

// =====================================================================
// Block-resolved sequential NMS + final compaction to d_out.
// Push-apply: 8 rows/iter via SELECTS (register-only; rule #20).
// =====================================================================
__global__ __launch_bounds__(256) void nms_out_kernel(
    const float* __restrict__ boxes_s, const float* __restrict__ sc_s,
    const unsigned long long* __restrict__ mask,
    const unsigned long long* __restrict__ diag, float* __restrict__ out) {
  int t = threadIdx.x;
  for (int e = t; e < (OUT_K * 4 + OUT_K); e += 256) out[e] = 0.f;
  __shared__ unsigned long long keepw[32];
  if (t < 64) {
    unsigned long long removed = 0ull;  // lanes 0..31 own word t
    if (t < 32) {
      keepw[t] = 0ull;
#pragma unroll
      for (int k = 0; k < 64; ++k) {
        int idx = t * 64 + k;
        if (idx >= PRE_K || sc_s[idx] < 0.f) removed |= (1ull << k);
      }
    }
    const int w = t & 31;
    const int half = t >> 5;
    unsigned int kept = 0;
    for (int b = 0; b < 32; ++b) {
      unsigned long long d = diag[b * 64 + t];  // coalesced 512B
      unsigned long long dead = __shfl(removed, b);
      unsigned long long alive = 0ull;
#pragma unroll
      for (int k = 0; k < 64; ++k) {
        unsigned long long dk = __shfl(d, k);
        if (!((dead >> k) & 1ull)) {
          alive |= (1ull << k);
          dead |= dk;
        }
      }
      if (t == 0) keepw[b] = alive;
      kept += (unsigned)__popcll(alive);
      if (kept >= (unsigned)OUT_K || b == 31) break;
      // push-apply: OR alive rows' mask into future words; 8 rows/iter.
      unsigned long long am = alive;
      const long long rb = (long long)b * 64;
      while (am) {
        int k0 = __ffsll(am) - 1; am &= am - 1;
        int k1 = k0, k2 = k0, k3 = k0, k4 = k0, k5 = k0, k6 = k0, k7 = k0;
        if (am) { k1 = __ffsll(am) - 1; am &= am - 1; }
        if (am) { k2 = __ffsll(am) - 1; am &= am - 1; }
        if (am) { k3 = __ffsll(am) - 1; am &= am - 1; }
        if (am) { k4 = __ffsll(am) - 1; am &= am - 1; }
        if (am) { k5 = __ffsll(am) - 1; am &= am - 1; }
        if (am) { k6 = __ffsll(am) - 1; am &= am - 1; }
        if (am) { k7 = __ffsll(am) - 1; am &= am - 1; }
        unsigned long long v0 = mask[(size_t)(rb + (half ? k1 : k0)) * 32 + w];
        unsigned long long v1 = mask[(size_t)(rb + (half ? k3 : k2)) * 32 + w];
        unsigned long long v2 = mask[(size_t)(rb + (half ? k5 : k4)) * 32 + w];
        unsigned long long v3 = mask[(size_t)(rb + (half ? k7 : k6)) * 32 + w];
        unsigned long long vv = v0 | v1 | v2 | v3;
        unsigned long long hv = __shfl(vv, w + 32);
        if (t < 32) removed |= vv | hv;
      }
    }
  }
  __syncthreads();
  __shared__ unsigned int wbase[32];
  if (t == 0) {
    unsigned int s = 0;
    for (int k = 0; k < 32; ++k) {
      wbase[k] = s;
      s += (unsigned)__popcll(keepw[k]);
    }
  }
  __syncthreads();
  for (int i = t; i < PRE_K; i += 256) {
    unsigned long long w2 = keepw[i >> 6];
    if ((w2 >> (i & 63)) & 1ull) {
      unsigned int pos =
          wbase[i >> 6] +
          (unsigned)__popcll(w2 & ((1ull << (i & 63)) - 1ull));
      if (pos < OUT_K) {
        out[pos * 4 + 0] = boxes_s[i * 4 + 0];
        out[pos * 4 + 1] = boxes_s[i * 4 + 1];
        out[pos * 4 + 2] = boxes_s[i * 4 + 2];
        out[pos * 4 + 3] = boxes_s[i * 4 + 3];
        out[OUT_K * 4 + pos] = sc_s[i];
      }
    }
  }
}

// =====================================================================
extern "C" void kernel_launch(void* const* d_in, const int* in_sizes, int n_in,
                              void* d_out, int out_size, void* d_ws,
                              size_t ws_size, hipStream_t stream) {
  const float* feat = (const float*)d_in[1];
  const float* convw = (const float*)d_in[2];
  const float* convb = (const float*)d_in[3];
  const float* clsw = (const float*)d_in[4];
  const float* clsb = (const float*)d_in[5];
  const float* regw = (const float*)d_in[6];
  const float* regb = (const float*)d_in[7];

  char* ws = (char*)d_ws;
  unsigned int* hist = (unsigned int*)(ws + OFF_HIST);
  unsigned int* state = (unsigned int*)(ws + OFF_STATE);
  unsigned long long* cand = (unsigned long long*)(ws + OFF_CAND);
  float* boxes_s = (float*)(ws + OFF_BOXS);
  float* sc_s = (float*)(ws + OFF_SCS);
  unsigned long long* mask = (unsigned long long*)(ws + OFF_MASK);
  unsigned long long* diag = (unsigned long long*)(ws + OFF_DIAG);
  uint4* AW_h = (uint4*)(ws + OFF_AWH);
  uint4* AW_m = (uint4*)(ws + OFF_AWM);
  uint4* AW_l = (uint4*)(ws + OFF_AWL);
  uint4* HwF_h = (uint4*)(ws + OFF_HWH);
  uint4* HwF_m = (uint4*)(ws + OFF_HWM);
  uint4* HwF_l = (uint4*)(ws + OFF_HWL);
  float* logits = (float*)(ws + OFF_LOGIT);
  unsigned short* Ph = (unsigned short*)(ws + OFF_PH);
  unsigned short* Pm = (unsigned short*)(ws + OFF_PM);
  unsigned short* Pl = (unsigned short*)(ws + OFF_PL);
  float* prop = (float*)(ws + OFF_PROP);
  float* score = (float*)(ws + OFF_SCORE);
  float* out = (float*)d_out;

  // zero hist + state (incl. tickets state[8..11])
  hipMemsetAsync(ws, 0, OFF_STATE + 64, stream);

  prep_all<<<1550, 256, 0, stream>>>(feat, convw, clsw, regw, Ph, Pm, Pl,
                                     AW_h, AW_m, AW_l, HwF_h, HwF_m, HwF_l);
  conv_mfma<<<dim3(13, 50), 256, 0, stream>>>(Ph, Pm, Pl, AW_h, AW_m, AW_l,
                                              HwF_h, HwF_m, HwF_l, convb,
                                              logits);
  finalize_kernel<<<157, 256, 0, stream>>>(logits, clsb, regb, prop, score,
                                           hist, state);
  for (int p = 1; p < 4; ++p)
    hist_scan_kernel<<<256, 256, 0, stream>>>(score, hist, state,
                                              &state[8 + p], p);
  collect_kernel<<<256, 256, 0, stream>>>(score, state, cand);
  sort_gather<<<1, 1024, 0, stream>>>(cand, state, prop, score, boxes_s, sc_s);
  iou_kernel<<<dim3(32, 32), 64, 0, stream>>>(boxes_s, mask, diag);
  nms_out_kernel<<<1, 256, 0, stream>>>(boxes_s, sc_s, mask, diag, out);
}

// Round 7
// 641.660 us; speedup vs baseline: 1.3163x; 1.3163x over previous
//
#include <hip/hip_runtime.h>
#include <math.h>

// ---------------- constants ----------------
#define FH 200
#define FW 200
#define HW 40000            // FH*FW
#define NUM_A 9
#define NANCH 360000        // HW*NUM_A
#define PRE_K 2000
#define OUT_K 1000
#define IMG_SZ 1600.0f
#define MIN_SZ 16.0f
#define NMS_TH 0.7f
#define BBOX_CLIP_F 4.135166556742356f   // log(1000/16)

// ---------------- workspace layout (bytes), total ~80.1 MB ----------------
// prop/score alias the PH plane region: planes are dead after conv_mfma,
// prop/score are written by finalize which runs after conv_mfma.
#define OFF_HIST   ((size_t)0)           // 256 u32 = 1024
#define OFF_STATE  ((size_t)1024)        // 16 u32 = 64 (incl tickets [8..11])
#define OFF_CAND   ((size_t)1088)        // 4096 u64 = 32768
#define OFF_BOXS   ((size_t)33856)       // 2000*4 f = 32000
#define OFF_SCS    ((size_t)65856)       // 2000 f = 8000
#define OFF_MASK   ((size_t)73856)       // 2000*32 u64 = 512000
#define OFF_DIAG   ((size_t)585856)      // 2048 u64 = 16384
#define OFF_AWH    ((size_t)602240)      // 73728*16 = 1179648
#define OFF_AWM    ((size_t)1781888)
#define OFF_AWL    ((size_t)2961536)
#define OFF_HWH    ((size_t)4141184)     // 1536*16 = 24576
#define OFF_HWM    ((size_t)4165760)
#define OFF_HWL    ((size_t)4190336)
#define OFF_LOGIT  ((size_t)4214912)     // 2 * 40000*45*4 = 14,400,000
#define OFF_PH     ((size_t)18614912)    // 8*40000*32*2 = 20,480,000
#define OFF_PM     ((size_t)39094912)
#define OFF_PL     ((size_t)59574912)    // end 80,054,912
#define OFF_PROP   ((size_t)18614912)    // alias PH (5,760,000)
#define OFF_SCORE  ((size_t)24374912)    // alias PH (1,440,000)

typedef __attribute__((ext_vector_type(8))) short short8;
typedef __attribute__((ext_vector_type(4))) float floatx4;
#define MFMA16(a, b, c) __builtin_amdgcn_mfma_f32_16x16x32_bf16(a, b, c, 0, 0, 0)

__device__ __forceinline__ unsigned short rne_bf16(float v) {
  unsigned int bb = __float_as_uint(v);
  return (unsigned short)((bb + 0x7FFFu + ((bb >> 16) & 1u)) >> 16);
}

// 3-way split: v = h + m + l + eps, |eps| <~ 2^-25 |v|
__device__ __forceinline__ void split3(float v, unsigned short& h,
                                       unsigned short& m, unsigned short& l) {
  h = rne_bf16(v);
  float r1 = v - __uint_as_float(((unsigned int)h) << 16);
  m = rne_bf16(r1);
  float r2 = r1 - __uint_as_float(((unsigned int)m) << 16);
  l = rne_bf16(r2);
}

// =====================================================================
// Fused prepass (one launch):
//   blocks [0,1256): split3 feat into 3 bf16 planes, layout [cib][px][32ci]
//   blocks [1256,1550): swizzle conv + head weights into MFMA A-fragment
//     order, 3-way split.
// =====================================================================
__global__ __launch_bounds__(256) void prep_all(
    const float* __restrict__ feat, const float* __restrict__ w,
    const float* __restrict__ cls_w, const float* __restrict__ reg_w,
    unsigned short* __restrict__ Ph, unsigned short* __restrict__ Pm,
    unsigned short* __restrict__ Pl, uint4* __restrict__ AW_h,
    uint4* __restrict__ AW_m, uint4* __restrict__ AW_l,
    uint4* __restrict__ HwF_h, uint4* __restrict__ HwF_m,
    uint4* __restrict__ HwF_l) {
  int bx = blockIdx.x;
  int t = threadIdx.x;
  if (bx < 1256) {
    int cib = bx & 7;
    int px = (bx >> 3) * 256 + t;
    if (px >= HW) return;
    unsigned short h[32], m[32], l[32];
#pragma unroll
    for (int ci = 0; ci < 32; ++ci)
      split3(feat[(size_t)(cib * 32 + ci) * HW + px], h[ci], m[ci], l[ci]);
    size_t base = ((size_t)cib * HW + px) * 32;
    uint4* dh = (uint4*)(Ph + base);
    uint4* dm = (uint4*)(Pm + base);
    uint4* dl = (uint4*)(Pl + base);
#pragma unroll
    for (int k = 0; k < 4; ++k) {
      uint4 vh, vm, vl;
      vh.x = h[k * 8 + 0] | (h[k * 8 + 1] << 16);
      vh.y = h[k * 8 + 2] | (h[k * 8 + 3] << 16);
      vh.z = h[k * 8 + 4] | (h[k * 8 + 5] << 16);
      vh.w = h[k * 8 + 6] | (h[k * 8 + 7] << 16);
      vm.x = m[k * 8 + 0] | (m[k * 8 + 1] << 16);
      vm.y = m[k * 8 + 2] | (m[k * 8 + 3] << 16);
      vm.z = m[k * 8 + 4] | (m[k * 8 + 5] << 16);
      vm.w = m[k * 8 + 6] | (m[k * 8 + 7] << 16);
      vl.x = l[k * 8 + 0] | (l[k * 8 + 1] << 16);
      vl.y = l[k * 8 + 2] | (l[k * 8 + 3] << 16);
      vl.z = l[k * 8 + 4] | (l[k * 8 + 5] << 16);
      vl.w = l[k * 8 + 6] | (l[k * 8 + 7] << 16);
      dh[k] = vh; dm[k] = vm; dl[k] = vl;
    }
    return;
  }
  int gid = (bx - 1256) * 256 + t;
  unsigned short h[8], m[8], l[8];
  if (gid < 73728) {
    int L = gid & 63;
    int idx = gid >> 6;            // (ctg*9+tap)*8 + cib
    int cib = idx & 7;
    int tmp = idx >> 3;
    int tap = tmp % 9;
    int ctg = tmp / 9;
    int co = ctg * 16 + (L & 15);
    int ci0 = cib * 32 + (L >> 4) * 8;
#pragma unroll
    for (int j = 0; j < 8; ++j)
      split3(w[(size_t)co * 2304 + (ci0 + j) * 9 + tap], h[j], m[j], l[j]);
    uint4 vh, vm, vl;
    vh.x = h[0] | (h[1] << 16); vh.y = h[2] | (h[3] << 16);
    vh.z = h[4] | (h[5] << 16); vh.w = h[6] | (h[7] << 16);
    vm.x = m[0] | (m[1] << 16); vm.y = m[2] | (m[3] << 16);
    vm.z = m[4] | (m[5] << 16); vm.w = m[6] | (m[7] << 16);
    vl.x = l[0] | (l[1] << 16); vl.y = l[2] | (l[3] << 16);
    vl.z = l[4] | (l[5] << 16); vl.w = l[6] | (l[7] << 16);
    AW_h[gid] = vh; AW_m[gid] = vm; AW_l[gid] = vl;
  } else if (gid < 73728 + 1536) {
    int g2 = gid - 73728;
    int L = g2 & 63;
    int idx = g2 >> 6;             // mt*8 + kb
    int kb = idx & 7;
    int mt = idx >> 3;
    int mm = mt * 16 + (L & 15);
    int co0 = kb * 32 + (L >> 4) * 8;
#pragma unroll
    for (int j = 0; j < 8; ++j) {
      float v = 0.f;
      if (mm < 9) v = cls_w[mm * 256 + co0 + j];
      else if (mm < 45) v = reg_w[(mm - 9) * 256 + co0 + j];
      split3(v, h[j], m[j], l[j]);
    }
    uint4 vh, vm, vl;
    vh.x = h[0] | (h[1] << 16); vh.y = h[2] | (h[3] << 16);
    vh.z = h[4] | (h[5] << 16); vh.w = h[6] | (h[7] << 16);
    vm.x = m[0] | (m[1] << 16); vm.y = m[2] | (m[3] << 16);
    vm.z = m[4] | (m[5] << 16); vm.w = m[6] | (m[7] << 16);
    vl.x = l[0] | (l[1] << 16); vl.y = l[2] | (l[3] << 16);
    vl.z = l[4] | (l[5] << 16); vl.w = l[6] | (l[7] << 16);
    HwF_h[g2] = vh; HwF_m[g2] = vm; HwF_l[g2] = vl;
  }
}

// =====================================================================
// Main conv+heads MFMA kernel. Block = R5's proven 128 co (cb half) x
// 128 px tile, grid 13x25x2, same staging, same per-block A footprint
// (1.77 MB unique — R6's 3.54 MB/block retile thrashed L2, reverted).
// CHANGED: wave remap (wg,cg)=(wv>>1,wv&1) owns 4 ctg x 4 rows instead
// of 2 ctg x 8 rows: halves the block's B-fragment ds_read_b128 count
// per tap (96->48) at unchanged MFMA count — conv was LDS-read-bound
// (measured 58% MfmaUtil == predicted LDS ceiling). The cg-paired waves
// read identical A addresses nearly in lockstep -> L1/L2 hits.
// Per-element MFMA chains identical => bit-identical output.
// =====================================================================
__global__ __launch_bounds__(256, 3) void conv_mfma(
    const unsigned short* __restrict__ Ph, const unsigned short* __restrict__ Pm,
    const unsigned short* __restrict__ Pl, const uint4* __restrict__ AW_h,
    const uint4* __restrict__ AW_m, const uint4* __restrict__ AW_l,
    const uint4* __restrict__ HwF_h, const uint4* __restrict__ HwF_m,
    const uint4* __restrict__ HwF_l, const float* __restrict__ bias,
    float* __restrict__ logits) {
  __shared__ alignas(16) unsigned short smem[26112];  // 52,224 B
  const int t = threadIdx.x;
  const int L = t & 63, wv = t >> 6;
  const int q = L >> 4, nl = L & 15;
  const int wg = wv >> 1;              // row-group: rows wg*4..wg*4+3
  const int cg = wv & 1;               // ctg-group: ctg cg*4..cg*4+3
  const int w0 = blockIdx.x * 16;
  const int h0 = blockIdx.y * 8;
  const int cb = blockIdx.z;

  floatx4 acc[4][4];                   // [ct][r]
#pragma unroll
  for (int ct = 0; ct < 4; ++ct)
#pragma unroll
    for (int r = 0; r < 4; ++r) acc[ct][r] = (floatx4)0.f;

  unsigned short* flh = smem;            // [10 rows][18 cols][40 u16-pad]
  unsigned short* flm = smem + 7200;
  unsigned short* fll = smem + 14400;

  for (int cib = 0; cib < 8; ++cib) {
    __syncthreads();
#pragma unroll
    for (int j = 0; j < 9; ++j) {
      const int p = j / 3;               // plane (compile-time after unroll)
      const int c = (j % 3) * 256 + t;   // chunk id in [0,768)
      if (c < 720) {
        int rr = (int)((unsigned)c / 72u);
        int rem = c - rr * 72;
        int cc = rem >> 2, q16 = rem & 3;
        int gr = h0 - 1 + rr, gc = w0 - 1 + cc;
        uint4 v; v.x = v.y = v.z = v.w = 0u;
        if ((unsigned)gr < (unsigned)FH && (unsigned)gc < (unsigned)FW) {
          const unsigned short* pp = (p == 0) ? Ph : (p == 1) ? Pm : Pl;
          v = *(const uint4*)(pp +
                ((size_t)(cib * HW + gr * FW + gc) * 32 + q16 * 8));
        }
        *(uint4*)(smem + p * 7200 + rr * 720 + cc * 40 + q16 * 8) = v;
      }
    }
    __syncthreads();
    __builtin_amdgcn_s_setprio(1);
    const int ctg0 = cb * 8 + cg * 4;
    for (int kh = 0; kh < 3; ++kh) {
      for (int kw = 0; kw < 3; ++kw) {
        const int tap = kh * 3 + kw;
        short8 ah[4], am[4], al[4];
#pragma unroll
        for (int ct = 0; ct < 4; ++ct) {
          const int ab = (((ctg0 + ct) * 9 + tap) * 8 + cib) * 64 + L;
          ah[ct] = ((const short8*)AW_h)[ab];
          am[ct] = ((const short8*)AW_m)[ab];
          al[ct] = ((const short8*)AW_l)[ab];
        }
        const int cbase = (nl + kw) * 40 + q * 8;
#pragma unroll
        for (int r = 0; r < 4; ++r) {
          const int off = (wg * 4 + r + kh) * 720 + cbase;
          short8 bh = *(const short8*)(flh + off);
          short8 bm = *(const short8*)(flm + off);
          short8 bl = *(const short8*)(fll + off);
#pragma unroll
          for (int ct = 0; ct < 4; ++ct) {
            acc[ct][r] = MFMA16(ah[ct], bh, acc[ct][r]);
            acc[ct][r] = MFMA16(ah[ct], bm, acc[ct][r]);
            acc[ct][r] = MFMA16(am[ct], bh, acc[ct][r]);
            acc[ct][r] = MFMA16(ah[ct], bl, acc[ct][r]);
            acc[ct][r] = MFMA16(am[ct], bm, acc[ct][r]);
            acc[ct][r] = MFMA16(al[ct], bh, acc[ct][r]);
          }
        }
      }
    }
    __builtin_amdgcn_s_setprio(0);
  }

  // ---- epilogue ----
  float bv[4][4];
#pragma unroll
  for (int ct = 0; ct < 4; ++ct)
#pragma unroll
    for (int i = 0; i < 4; ++i)
      bv[ct][i] = bias[cb * 128 + (cg * 4 + ct) * 16 + q * 4 + i];

  unsigned short* xlh = smem;           // [64 px][136 co-pad] u16
  unsigned short* xlm = smem + 8704;
  unsigned short* xll = smem + 17408;

  for (int hp = 0; hp < 2; ++hp) {
    __syncthreads();
    if (wg == hp) {
#pragma unroll
      for (int ct = 0; ct < 4; ++ct) {
#pragma unroll
        for (int rr = 0; rr < 4; ++rr) {
          unsigned short xh[4], xm[4], xl_[4];
#pragma unroll
          for (int i = 0; i < 4; ++i) {
            float xv = fmaxf(acc[ct][rr][i] + bv[ct][i], 0.f);
            split3(xv, xh[i], xm[i], xl_[i]);
          }
          int px_l = rr * 16 + nl;
          int co_l = (cg * 4 + ct) * 16 + q * 4;
          uint2 ph, pm, pl;
          ph.x = xh[0] | (xh[1] << 16); ph.y = xh[2] | (xh[3] << 16);
          pm.x = xm[0] | (xm[1] << 16); pm.y = xm[2] | (xm[3] << 16);
          pl.x = xl_[0] | (xl_[1] << 16); pl.y = xl_[2] | (xl_[3] << 16);
          *(uint2*)(xlh + px_l * 136 + co_l) = ph;
          *(uint2*)(xlm + px_l * 136 + co_l) = pm;
          *(uint2*)(xll + px_l * 136 + co_l) = pl;
        }
      }
    }
    __syncthreads();
    floatx4 ha[3];
#pragma unroll
    for (int mt = 0; mt < 3; ++mt) ha[mt] = (floatx4)0.f;
    for (int ks = 0; ks < 4; ++ks) {
      const int off = (wv * 16 + nl) * 136 + ks * 32 + q * 8;
      short8 bh = *(const short8*)(xlh + off);
      short8 bm = *(const short8*)(xlm + off);
      short8 bl = *(const short8*)(xll + off);
#pragma unroll
      for (int mt = 0; mt < 3; ++mt) {
        const int hb = (mt * 8 + cb * 4 + ks) * 64 + L;
        short8 hh = ((const short8*)HwF_h)[hb];
        short8 hm = ((const short8*)HwF_m)[hb];
        short8 hl = ((const short8*)HwF_l)[hb];
        ha[mt] = MFMA16(hh, bh, ha[mt]);
        ha[mt] = MFMA16(hh, bm, ha[mt]);
        ha[mt] = MFMA16(hm, bh, ha[mt]);
        ha[mt] = MFMA16(hh, bl, ha[mt]);
        ha[mt] = MFMA16(hm, bm, ha[mt]);
        ha[mt] = MFMA16(hl, bh, ha[mt]);
      }
    }
    int gr = h0 + hp * 4 + wv;
    int gc = w0 + nl;
    if (gc < FW) {
      float* lp = logits + ((size_t)cb * HW + (size_t)(gr * FW + gc)) * 45;
#pragma unroll
      for (int mt = 0; mt < 3; ++mt)
#pragma unroll
        for (int i = 0; i < 4; ++i) {
          int head = mt * 16 + q * 4 + i;
          if (head < 45) lp[head] = ha[mt][i];
        }
    }
  }
}

// =====================================================================
// finalize — sum cb partials + bias + anchors + deltas + sigmoid.
// Fused radix hist pass-0 AND scan-0 (last-block ticket).
// =====================================================================
__global__ __launch_bounds__(256) void finalize_kernel(
    const float* __restrict__ logits, const float* __restrict__ cls_b,
    const float* __restrict__ reg_b, float* __restrict__ prop,
    float* __restrict__ score, unsigned int* __restrict__ hist,
    unsigned int* __restrict__ state) {
  __shared__ unsigned int hsh[256], s1[256];
  __shared__ int lastb;
  int t = threadIdx.x;
  hsh[t] = 0u;
  __syncthreads();
  int px = blockIdx.x * 256 + t;
  if (px < HW) {
    float A[45];
    const float* lpA = logits + (size_t)px * 45;
    const float* lpB = logits + (size_t)HW * 45 + (size_t)px * 45;
#pragma unroll
    for (int i = 0; i < 45; ++i) A[i] = lpA[i] + lpB[i];
    const float scv[3] = {128.f, 256.f, 512.f};
    const float arv[3] = {0.5f, 1.f, 2.f};
    float sx = (float)(px % FW) * 8.0f;
    float sy = (float)(px / FW) * 8.0f;
#pragma unroll
    for (int a = 0; a < NUM_A; ++a) {
      int ai = a / 3, si = a % 3;
      float hr = sqrtf(arv[ai]);
      float wr = 1.0f / hr;
      float rw = nearbyintf(wr * scv[si] * 0.5f);
      float rh = nearbyintf(hr * scv[si] * 0.5f);
      float ax0 = sx - rw, ay0 = sy - rh, ax1 = sx + rw, ay1 = sy + rh;
      float aw = ax1 - ax0, ah = ay1 - ay0;
      float cx = ax0 + 0.5f * aw, cy = ay0 + 0.5f * ah;
      float dx = A[9 + a * 4 + 0] + reg_b[a * 4 + 0];
      float dy = A[9 + a * 4 + 1] + reg_b[a * 4 + 1];
      float dw = fminf(A[9 + a * 4 + 2] + reg_b[a * 4 + 2], BBOX_CLIP_F);
      float dh = fminf(A[9 + a * 4 + 3] + reg_b[a * 4 + 3], BBOX_CLIP_F);
      float pcx = dx * aw + cx;
      float pcy = dy * ah + cy;
      float pw = expf(dw) * aw;
      float ph = expf(dh) * ah;
      size_t base = (size_t)(px * NUM_A + a) * 4;
      prop[base + 0] = pcx - 0.5f * pw;
      prop[base + 1] = pcy - 0.5f * ph;
      prop[base + 2] = pcx + 0.5f * pw;
      prop[base + 3] = pcy + 0.5f * ph;
      float lg = A[a] + cls_b[a];
      float sv = 1.0f / (1.0f + expf(-lg));
      score[px * NUM_A + a] = sv;
      atomicAdd(&hsh[__float_as_uint(sv) >> 24], 1u);
    }
  }
  __syncthreads();
  if (hsh[t]) atomicAdd(&hist[t], hsh[t]);
  __syncthreads();
  if (t == 0) lastb = (atomicAdd(&state[8], 1u) == gridDim.x - 1u) ? 1 : 0;
  __syncthreads();
  if (!lastb) return;
  __threadfence();
  // ---- scan pass 0 ----
  unsigned int hv = hist[t];
  hist[t] = 0u;
  hsh[t] = hv;
  __syncthreads();
  unsigned int* A = hsh;
  unsigned int* B = s1;
  for (int off = 1; off < 256; off <<= 1) {
    B[t] = A[t] + ((t + off < 256) ? A[t + off] : 0u);
    __syncthreads();
    unsigned int* tmp = A; A = B; B = tmp;
  }
  unsigned int rem = (unsigned)PRE_K;
  unsigned int suf = A[t];
  unsigned int sufn = (t < 255) ? A[t + 1] : 0u;
  if (suf >= rem && sufn < rem) {
    state[0] = (unsigned int)t;
    state[1] = rem - sufn;
  }
}

// =====================================================================
// Radix passes 1..3: histogram + fused last-block scan (ticket).
// =====================================================================
__global__ __launch_bounds__(256) void hist_scan_kernel(
    const float* __restrict__ score, unsigned int* __restrict__ hist,
    unsigned int* __restrict__ state, unsigned int* __restrict__ ticket,
    int pass) {
  __shared__ unsigned int h[256], s1[256];
  __shared__ int lastb;
  int t = threadIdx.x;
  h[t] = 0;
  __syncthreads();
  unsigned int prefix = state[0];
  int shift = 24 - 8 * pass;
  for (int i = blockIdx.x * 256 + t; i < NANCH; i += gridDim.x * 256) {
    unsigned int key = __float_as_uint(score[i]);
    if ((key >> (32 - 8 * pass)) == prefix)
      atomicAdd(&h[(key >> shift) & 255u], 1u);
  }
  __syncthreads();
  if (h[t]) atomicAdd(&hist[t], h[t]);
  __syncthreads();
  if (t == 0) lastb = (atomicAdd(ticket, 1u) == gridDim.x - 1u) ? 1 : 0;
  __syncthreads();
  if (!lastb) return;
  __threadfence();
  unsigned int hv = hist[t];
  hist[t] = 0u;
  h[t] = hv;
  __syncthreads();
  unsigned int* A = h;
  unsigned int* B = s1;
  for (int off = 1; off < 256; off <<= 1) {
    B[t] = A[t] + ((t + off < 256) ? A[t + off] : 0u);
    __syncthreads();
    unsigned int* tmp = A; A = B; B = tmp;
  }
  unsigned int rem = state[1];
  unsigned int suf = A[t];
  unsigned int sufn = (t < 255) ? A[t + 1] : 0u;
  if (suf >= rem && sufn < rem) {
    state[0] = (prefix << 8) | (unsigned int)t;
    state[1] = rem - sufn;
  }
}

__global__ __launch_bounds__(256) void collect_kernel(
    const float* __restrict__ score, unsigned int* __restrict__ state,
    unsigned long long* __restrict__ cand) {
  unsigned int T = state[0];
  for (int i = blockIdx.x * 256 + threadIdx.x; i < NANCH; i += gridDim.x * 256) {
    unsigned int key = __float_as_uint(score[i]);
    if (key >= T) {
      unsigned int pos = atomicAdd(&state[4], 1u);
      if (pos < 4096u)
        cand[pos] = ((unsigned long long)key << 32) |
                    (unsigned long long)(~(unsigned int)i);
    }
  }
}

// =====================================================================
// Bitonic sort + gather + clip + valid + stable partition
// =====================================================================
__global__ __launch_bounds__(1024) void sort_gather(
    const unsigned long long* __restrict__ cand,
    const unsigned int* __restrict__ state, const float* __restrict__ prop,
    const float* __restrict__ score, float* __restrict__ boxes_s,
    float* __restrict__ sc_s) {
  __shared__ unsigned long long sk[4096];
  int t = threadIdx.x;
  unsigned int cnt = state[4];
  if (cnt > 4096u) cnt = 4096u;
  for (int e = t; e < 4096; e += 1024) sk[e] = (e < (int)cnt) ? cand[e] : 0ull;
  __syncthreads();
  for (int k = 2; k <= 4096; k <<= 1) {
    for (int j = k >> 1; j > 0; j >>= 1) {
      for (int i = t; i < 4096; i += 1024) {
        int l = i ^ j;
        if (l > i) {
          unsigned long long a = sk[i], bb = sk[l];
          bool up = ((i & k) == 0);
          bool sw = up ? (a < bb) : (a > bb);
          if (sw) { sk[i] = bb; sk[l] = a; }
        }
      }
      __syncthreads();
    }
  }
  float bx[2][4];
  float sc2[2] = {-1.f, -1.f};
  bool valid2[2] = {false, false};
#pragma unroll
  for (int s = 0; s < 2; ++s) {
    int i = t + s * 1024;
    bx[s][0] = bx[s][1] = bx[s][2] = bx[s][3] = 0.f;
    if (i < PRE_K) {
      unsigned long long v = sk[i];
      unsigned int idx = ~(unsigned int)(v & 0xFFFFFFFFull);
      float4 p = *(const float4*)(prop + (size_t)idx * 4);
      float x0 = fminf(fmaxf(p.x, 0.f), IMG_SZ);
      float y0 = fminf(fmaxf(p.y, 0.f), IMG_SZ);
      float x1 = fminf(fmaxf(p.z, 0.f), IMG_SZ);
      float y1 = fminf(fmaxf(p.w, 0.f), IMG_SZ);
      bool valid = (x1 - x0 >= MIN_SZ) && (y1 - y0 >= MIN_SZ);
      bx[s][0] = x0; bx[s][1] = y0; bx[s][2] = x1; bx[s][3] = y1;
      valid2[s] = valid;
      sc2[s] = valid ? score[idx] : -1.0f;
    }
  }
  __syncthreads();
  int* A = (int*)sk;
  int* B = A + 2048;
#pragma unroll
  for (int s = 0; s < 2; ++s) {
    int i = t + s * 1024;
    A[i] = (i < PRE_K && valid2[s]) ? 1 : 0;
  }
  __syncthreads();
  for (int off = 1; off < 2048; off <<= 1) {
#pragma unroll
    for (int s = 0; s < 2; ++s) {
      int i = t + s * 1024;
      B[i] = A[i] + ((i >= off) ? A[i - off] : 0);
    }
    __syncthreads();
    int* tmp = A; A = B; B = tmp;
  }
  int total = A[2047];
#pragma unroll
  for (int s = 0; s < 2; ++s) {
    int i = t + s * 1024;
    if (i < PRE_K) {
      int inc = A[i];
      int pos = valid2[s] ? (inc - 1) : (total + (i - inc));
      boxes_s[pos * 4 + 0] = bx[s][0];
      boxes_s[pos * 4 + 1] = bx[s][1];
      boxes_s[pos * 4 + 2] = bx[s][2];
      boxes_s[pos * 4 + 3] = bx[s][3];
      sc_s[pos] = sc2[s];
    }
  }
}

// =====================================================================
// IoU suppression bitmask (+ coalesced diag words)
// =====================================================================
__global__ __launch_bounds__(64) void iou_kernel(
    const float* __restrict__ boxes_s, unsigned long long* __restrict__ mask,
    unsigned long long* __restrict__ diag) {
  int bi = blockIdx.y, bj = blockIdx.x;
  int t = threadIdx.x;
  __shared__ float4 cb[64];
  int jc = bj * 64 + t;
  float4 z; z.x = z.y = z.z = z.w = 0.f;
  cb[t] = (jc < PRE_K) ? *(const float4*)(boxes_s + (size_t)jc * 4) : z;
  __syncthreads();
  int i = bi * 64 + t;
  if (i >= PRE_K) return;
  float4 a = *(const float4*)(boxes_s + (size_t)i * 4);
  float areaA = (a.z - a.x) * (a.w - a.y);
  unsigned long long bits = 0ull;
  for (int jj = 0; jj < 64; ++jj) {
    int j = bj * 64 + jj;
    if (j < PRE_K && j > i) {
      float4 b = cb[jj];
      float areaB = (b.z - b.x) * (b.w - b.y);
      float ltx = fmaxf(a.x, b.x), lty = fmaxf(a.y, b.y);
      float rbx = fminf(a.z, b.z), rby = fminf(a.w, b.w);
      float w = fmaxf(rbx - ltx, 0.f), h = fmaxf(rby - lty, 0.f);
      float inter = w * h;
      float iou = inter / (areaA + areaB - inter + 1e-9f);
      if (iou > NMS_TH) bits |= (1ull << jj);
    }
  }
  mask[(size_t)i * 32 + bj] = bits;
  if (bi == bj) diag[i] = bits;
}

// =====================================================================
// Block-resolved sequential NMS + final compaction to d_out.
// Push-apply: 8 rows/iter via SELECTS (register-only; rule #20).
// =====================================================================
__global__ __launch_bounds__(256) void nms_out_kernel(
    const float* __restrict__ boxes_s, const float* __restrict__ sc_s,
    const unsigned long long* __restrict__ mask,
    const unsigned long long* __restrict__ diag, float* __restrict__ out) {
  int t = threadIdx.x;
  for (int e = t; e < (OUT_K * 4 + OUT_K); e += 256) out[e] = 0.f;
  __shared__ unsigned long long keepw[32];
  if (t < 64) {
    unsigned long long removed = 0ull;  // lanes 0..31 own word t
    if (t < 32) {
      keepw[t] = 0ull;
#pragma unroll
      for (int k = 0; k < 64; ++k) {
        int idx = t * 64 + k;
        if (idx >= PRE_K || sc_s[idx] < 0.f) removed |= (1ull << k);
      }
    }
    const int w = t & 31;
    const int half = t >> 5;
    unsigned int kept = 0;
    for (int b = 0; b < 32; ++b) {
      unsigned long long d = diag[b * 64 + t];  // coalesced 512B
      unsigned long long dead = __shfl(removed, b);
      unsigned long long alive = 0ull;
#pragma unroll
      for (int k = 0; k < 64; ++k) {
        unsigned long long dk = __shfl(d, k);
        if (!((dead >> k) & 1ull)) {
          alive |= (1ull << k);
          dead |= dk;
        }
      }
      if (t == 0) keepw[b] = alive;
      kept += (unsigned)__popcll(alive);
      if (kept >= (unsigned)OUT_K || b == 31) break;
      // push-apply: OR alive rows' mask into future words; 8 rows/iter.
      unsigned long long am = alive;
      const long long rb = (long long)b * 64;
      while (am) {
        int k0 = __ffsll(am) - 1; am &= am - 1;
        int k1 = k0, k2 = k0, k3 = k0, k4 = k0, k5 = k0, k6 = k0, k7 = k0;
        if (am) { k1 = __ffsll(am) - 1; am &= am - 1; }
        if (am) { k2 = __ffsll(am) - 1; am &= am - 1; }
        if (am) { k3 = __ffsll(am) - 1; am &= am - 1; }
        if (am) { k4 = __ffsll(am) - 1; am &= am - 1; }
        if (am) { k5 = __ffsll(am) - 1; am &= am - 1; }
        if (am) { k6 = __ffsll(am) - 1; am &= am - 1; }
        if (am) { k7 = __ffsll(am) - 1; am &= am - 1; }
        unsigned long long v0 = mask[(size_t)(rb + (half ? k1 : k0)) * 32 + w];
        unsigned long long v1 = mask[(size_t)(rb + (half ? k3 : k2)) * 32 + w];
        unsigned long long v2 = mask[(size_t)(rb + (half ? k5 : k4)) * 32 + w];
        unsigned long long v3 = mask[(size_t)(rb + (half ? k7 : k6)) * 32 + w];
        unsigned long long vv = v0 | v1 | v2 | v3;
        unsigned long long hv = __shfl(vv, w + 32);
        if (t < 32) removed |= vv | hv;
      }
    }
  }
  __syncthreads();
  __shared__ unsigned int wbase[32];
  if (t == 0) {
    unsigned int s = 0;
    for (int k = 0; k < 32; ++k) {
      wbase[k] = s;
      s += (unsigned)__popcll(keepw[k]);
    }
  }
  __syncthreads();
  for (int i = t; i < PRE_K; i += 256) {
    unsigned long long w2 = keepw[i >> 6];
    if ((w2 >> (i & 63)) & 1ull) {
      unsigned int pos =
          wbase[i >> 6] +
          (unsigned)__popcll(w2 & ((1ull << (i & 63)) - 1ull));
      if (pos < OUT_K) {
        out[pos * 4 + 0] = boxes_s[i * 4 + 0];
        out[pos * 4 + 1] = boxes_s[i * 4 + 1];
        out[pos * 4 + 2] = boxes_s[i * 4 + 2];
        out[pos * 4 + 3] = boxes_s[i * 4 + 3];
        out[OUT_K * 4 + pos] = sc_s[i];
      }
    }
  }
}

// =====================================================================
extern "C" void kernel_launch(void* const* d_in, const int* in_sizes, int n_in,
                              void* d_out, int out_size, void* d_ws,
                              size_t ws_size, hipStream_t stream) {
  const float* feat = (const float*)d_in[1];
  const float* convw = (const float*)d_in[2];
  const float* convb = (const float*)d_in[3];
  const float* clsw = (const float*)d_in[4];
  const float* clsb = (const float*)d_in[5];
  const float* regw = (const float*)d_in[6];
  const float* regb = (const float*)d_in[7];

  char* ws = (char*)d_ws;
  unsigned int* hist = (unsigned int*)(ws + OFF_HIST);
  unsigned int* state = (unsigned int*)(ws + OFF_STATE);
  unsigned long long* cand = (unsigned long long*)(ws + OFF_CAND);
  float* boxes_s = (float*)(ws + OFF_BOXS);
  float* sc_s = (float*)(ws + OFF_SCS);
  unsigned long long* mask = (unsigned long long*)(ws + OFF_MASK);
  unsigned long long* diag = (unsigned long long*)(ws + OFF_DIAG);
  uint4* AW_h = (uint4*)(ws + OFF_AWH);
  uint4* AW_m = (uint4*)(ws + OFF_AWM);
  uint4* AW_l = (uint4*)(ws + OFF_AWL);
  uint4* HwF_h = (uint4*)(ws + OFF_HWH);
  uint4* HwF_m = (uint4*)(ws + OFF_HWM);
  uint4* HwF_l = (uint4*)(ws + OFF_HWL);
  float* logits = (float*)(ws + OFF_LOGIT);
  unsigned short* Ph = (unsigned short*)(ws + OFF_PH);
  unsigned short* Pm = (unsigned short*)(ws + OFF_PM);
  unsigned short* Pl = (unsigned short*)(ws + OFF_PL);
  float* prop = (float*)(ws + OFF_PROP);
  float* score = (float*)(ws + OFF_SCORE);
  float* out = (float*)d_out;

  // zero hist + state (incl. tickets state[8..11])
  hipMemsetAsync(ws, 0, OFF_STATE + 64, stream);

  prep_all<<<1550, 256, 0, stream>>>(feat, convw, clsw, regw, Ph, Pm, Pl,
                                     AW_h, AW_m, AW_l, HwF_h, HwF_m, HwF_l);
  conv_mfma<<<dim3(13, 25, 2), 256, 0, stream>>>(Ph, Pm, Pl, AW_h, AW_m, AW_l,
                                                 HwF_h, HwF_m, HwF_l, convb,
                                                 logits);
  finalize_kernel<<<157, 256, 0, stream>>>(logits, clsb, regb, prop, score,
                                           hist, state);
  for (int p = 1; p < 4; ++p)
    hist_scan_kernel<<<256, 256, 0, stream>>>(score, hist, state,
                                              &state[8 + p], p);
  collect_kernel<<<256, 256, 0, stream>>>(score, state, cand);
  sort_gather<<<1, 1024, 0, stream>>>(cand, state, prop, score, boxes_s, sc_s);
  iou_kernel<<<dim3(32, 32), 64, 0, stream>>>(boxes_s, mask, diag);
  nms_out_kernel<<<1, 256, 0, stream>>>(boxes_s, sc_s, mask, diag, out);
}

// Round 8
// 579.890 us; speedup vs baseline: 1.4566x; 1.1065x over previous
//
#include <hip/hip_runtime.h>
#include <math.h>

// ---------------- constants ----------------
#define FH 200
#define FW 200
#define HW 40000            // FH*FW
#define NUM_A 9
#define NANCH 360000        // HW*NUM_A
#define PRE_K 2000
#define OUT_K 1000
#define IMG_SZ 1600.0f
#define MIN_SZ 16.0f
#define NMS_TH 0.7f
#define BBOX_CLIP_F 4.135166556742356f   // log(1000/16)

// ---------------- workspace layout (bytes), total ~80.1 MB ----------------
// prop/score alias the PH plane region: planes are dead after conv_mfma,
// prop/score are written by finalize which runs after conv_mfma.
#define OFF_HIST   ((size_t)0)           // 256 u32 = 1024
#define OFF_STATE  ((size_t)1024)        // 16 u32 = 64 (incl tickets [8..11])
#define OFF_CAND   ((size_t)1088)        // 4096 u64 = 32768
#define OFF_BOXS   ((size_t)33856)       // 2000*4 f = 32000
#define OFF_SCS    ((size_t)65856)       // 2000 f = 8000
#define OFF_MASK   ((size_t)73856)       // 2000*32 u64 = 512000
#define OFF_DIAG   ((size_t)585856)      // 2048 u64 = 16384
#define OFF_AWH    ((size_t)602240)      // 73728*16 = 1179648
#define OFF_AWM    ((size_t)1781888)
#define OFF_AWL    ((size_t)2961536)
#define OFF_HWH    ((size_t)4141184)     // 1536*16 = 24576
#define OFF_HWM    ((size_t)4165760)
#define OFF_HWL    ((size_t)4190336)
#define OFF_LOGIT  ((size_t)4214912)     // 2 * 40000*45*4 = 14,400,000
#define OFF_PH     ((size_t)18614912)    // 8*40000*32*2 = 20,480,000
#define OFF_PM     ((size_t)39094912)
#define OFF_PL     ((size_t)59574912)    // end 80,054,912
#define OFF_PROP   ((size_t)18614912)    // alias PH (5,760,000)
#define OFF_SCORE  ((size_t)24374912)    // alias PH (1,440,000)

typedef __attribute__((ext_vector_type(8))) short short8;
typedef __attribute__((ext_vector_type(4))) float floatx4;
#define MFMA16(a, b, c) __builtin_amdgcn_mfma_f32_16x16x32_bf16(a, b, c, 0, 0, 0)

__device__ __forceinline__ unsigned short rne_bf16(float v) {
  unsigned int bb = __float_as_uint(v);
  return (unsigned short)((bb + 0x7FFFu + ((bb >> 16) & 1u)) >> 16);
}

// 3-way split: v = h + m + l + eps, |eps| <~ 2^-25 |v|
__device__ __forceinline__ void split3(float v, unsigned short& h,
                                       unsigned short& m, unsigned short& l) {
  h = rne_bf16(v);
  float r1 = v - __uint_as_float(((unsigned int)h) << 16);
  m = rne_bf16(r1);
  float r2 = r1 - __uint_as_float(((unsigned int)m) << 16);
  l = rne_bf16(r2);
}

// =====================================================================
// Fused prepass (one launch):
//   blocks [0,1256): split3 feat into 3 bf16 planes, layout [cib][px][32ci]
//   blocks [1256,1550): swizzle conv + head weights into MFMA A-fragment
//     order, 3-way split.
// =====================================================================
__global__ __launch_bounds__(256) void prep_all(
    const float* __restrict__ feat, const float* __restrict__ w,
    const float* __restrict__ cls_w, const float* __restrict__ reg_w,
    unsigned short* __restrict__ Ph, unsigned short* __restrict__ Pm,
    unsigned short* __restrict__ Pl, uint4* __restrict__ AW_h,
    uint4* __restrict__ AW_m, uint4* __restrict__ AW_l,
    uint4* __restrict__ HwF_h, uint4* __restrict__ HwF_m,
    uint4* __restrict__ HwF_l) {
  int bx = blockIdx.x;
  int t = threadIdx.x;
  if (bx < 1256) {
    int cib = bx & 7;
    int px = (bx >> 3) * 256 + t;
    if (px >= HW) return;
    unsigned short h[32], m[32], l[32];
#pragma unroll
    for (int ci = 0; ci < 32; ++ci)
      split3(feat[(size_t)(cib * 32 + ci) * HW + px], h[ci], m[ci], l[ci]);
    size_t base = ((size_t)cib * HW + px) * 32;
    uint4* dh = (uint4*)(Ph + base);
    uint4* dm = (uint4*)(Pm + base);
    uint4* dl = (uint4*)(Pl + base);
#pragma unroll
    for (int k = 0; k < 4; ++k) {
      uint4 vh, vm, vl;
      vh.x = h[k * 8 + 0] | (h[k * 8 + 1] << 16);
      vh.y = h[k * 8 + 2] | (h[k * 8 + 3] << 16);
      vh.z = h[k * 8 + 4] | (h[k * 8 + 5] << 16);
      vh.w = h[k * 8 + 6] | (h[k * 8 + 7] << 16);
      vm.x = m[k * 8 + 0] | (m[k * 8 + 1] << 16);
      vm.y = m[k * 8 + 2] | (m[k * 8 + 3] << 16);
      vm.z = m[k * 8 + 4] | (m[k * 8 + 5] << 16);
      vm.w = m[k * 8 + 6] | (m[k * 8 + 7] << 16);
      vl.x = l[k * 8 + 0] | (l[k * 8 + 1] << 16);
      vl.y = l[k * 8 + 2] | (l[k * 8 + 3] << 16);
      vl.z = l[k * 8 + 4] | (l[k * 8 + 5] << 16);
      vl.w = l[k * 8 + 6] | (l[k * 8 + 7] << 16);
      dh[k] = vh; dm[k] = vm; dl[k] = vl;
    }
    return;
  }
  int gid = (bx - 1256) * 256 + t;
  unsigned short h[8], m[8], l[8];
  if (gid < 73728) {
    int L = gid & 63;
    int idx = gid >> 6;            // (ctg*9+tap)*8 + cib
    int cib = idx & 7;
    int tmp = idx >> 3;
    int tap = tmp % 9;
    int ctg = tmp / 9;
    int co = ctg * 16 + (L & 15);
    int ci0 = cib * 32 + (L >> 4) * 8;
#pragma unroll
    for (int j = 0; j < 8; ++j)
      split3(w[(size_t)co * 2304 + (ci0 + j) * 9 + tap], h[j], m[j], l[j]);
    uint4 vh, vm, vl;
    vh.x = h[0] | (h[1] << 16); vh.y = h[2] | (h[3] << 16);
    vh.z = h[4] | (h[5] << 16); vh.w = h[6] | (h[7] << 16);
    vm.x = m[0] | (m[1] << 16); vm.y = m[2] | (m[3] << 16);
    vm.z = m[4] | (m[5] << 16); vm.w = m[6] | (m[7] << 16);
    vl.x = l[0] | (l[1] << 16); vl.y = l[2] | (l[3] << 16);
    vl.z = l[4] | (l[5] << 16); vl.w = l[6] | (l[7] << 16);
    AW_h[gid] = vh; AW_m[gid] = vm; AW_l[gid] = vl;
  } else if (gid < 73728 + 1536) {
    int g2 = gid - 73728;
    int L = g2 & 63;
    int idx = g2 >> 6;             // mt*8 + kb
    int kb = idx & 7;
    int mt = idx >> 3;
    int mm = mt * 16 + (L & 15);
    int co0 = kb * 32 + (L >> 4) * 8;
#pragma unroll
    for (int j = 0; j < 8; ++j) {
      float v = 0.f;
      if (mm < 9) v = cls_w[mm * 256 + co0 + j];
      else if (mm < 45) v = reg_w[(mm - 9) * 256 + co0 + j];
      split3(v, h[j], m[j], l[j]);
    }
    uint4 vh, vm, vl;
    vh.x = h[0] | (h[1] << 16); vh.y = h[2] | (h[3] << 16);
    vh.z = h[4] | (h[5] << 16); vh.w = h[6] | (h[7] << 16);
    vm.x = m[0] | (m[1] << 16); vm.y = m[2] | (m[3] << 16);
    vm.z = m[4] | (m[5] << 16); vm.w = m[6] | (m[7] << 16);
    vl.x = l[0] | (l[1] << 16); vl.y = l[2] | (l[3] << 16);
    vl.z = l[4] | (l[5] << 16); vl.w = l[6] | (l[7] << 16);
    HwF_h[g2] = vh; HwF_m[g2] = vm; HwF_l[g2] = vl;
  }
}

// =====================================================================
// Main conv+heads MFMA kernel — EXACT round-3/4 form (verified 233 us,
// MfmaUtil 58%, VGPR 76). R5 prefetch was null; R6 retile and R7 wave
// remap both regressed (A-traffic dominates any B-read saving). This
// config is the measured local optimum: 2 ctg x 8 rows per wave,
// 1.77 MB A-footprint/block, 3 blocks/CU.
// =====================================================================
__global__ __launch_bounds__(256, 3) void conv_mfma(
    const unsigned short* __restrict__ Ph, const unsigned short* __restrict__ Pm,
    const unsigned short* __restrict__ Pl, const uint4* __restrict__ AW_h,
    const uint4* __restrict__ AW_m, const uint4* __restrict__ AW_l,
    const uint4* __restrict__ HwF_h, const uint4* __restrict__ HwF_m,
    const uint4* __restrict__ HwF_l, const float* __restrict__ bias,
    float* __restrict__ logits) {
  __shared__ alignas(16) unsigned short smem[26112];  // 52,224 B
  const int t = threadIdx.x;
  const int L = t & 63, wv = t >> 6;
  const int q = L >> 4, nl = L & 15;
  const int w0 = blockIdx.x * 16;
  const int h0 = blockIdx.y * 8;
  const int cb = blockIdx.z;

  floatx4 acc[2][8];
#pragma unroll
  for (int ct = 0; ct < 2; ++ct)
#pragma unroll
    for (int r = 0; r < 8; ++r) acc[ct][r] = (floatx4)0.f;

  unsigned short* flh = smem;            // [10 rows][18 cols][40 u16-pad]
  unsigned short* flm = smem + 7200;
  unsigned short* fll = smem + 14400;

  for (int cib = 0; cib < 8; ++cib) {
    __syncthreads();
#pragma unroll
    for (int j = 0; j < 9; ++j) {
      const int p = j / 3;               // plane (compile-time after unroll)
      const int c = (j % 3) * 256 + t;   // chunk id in [0,768)
      if (c < 720) {
        int rr = (int)((unsigned)c / 72u);
        int rem = c - rr * 72;
        int cc = rem >> 2, q16 = rem & 3;
        int gr = h0 - 1 + rr, gc = w0 - 1 + cc;
        uint4 v; v.x = v.y = v.z = v.w = 0u;
        if ((unsigned)gr < (unsigned)FH && (unsigned)gc < (unsigned)FW) {
          const unsigned short* pp = (p == 0) ? Ph : (p == 1) ? Pm : Pl;
          v = *(const uint4*)(pp +
                ((size_t)(cib * HW + gr * FW + gc) * 32 + q16 * 8));
        }
        *(uint4*)(smem + p * 7200 + rr * 720 + cc * 40 + q16 * 8) = v;
      }
    }
    __syncthreads();
    __builtin_amdgcn_s_setprio(1);
    const int ctg0 = cb * 8 + wv * 2;
    for (int kh = 0; kh < 3; ++kh) {
      for (int kw = 0; kw < 3; ++kw) {
        const int tap = kh * 3 + kw;
        const int abase = ((ctg0 * 9 + tap) * 8 + cib) * 64 + L;
        const int abase1 = abase + 9 * 8 * 64;
        short8 ah0 = ((const short8*)AW_h)[abase];
        short8 am0 = ((const short8*)AW_m)[abase];
        short8 al0 = ((const short8*)AW_l)[abase];
        short8 ah1 = ((const short8*)AW_h)[abase1];
        short8 am1 = ((const short8*)AW_m)[abase1];
        short8 al1 = ((const short8*)AW_l)[abase1];
        const int cbase = (nl + kw) * 40 + q * 8;
#pragma unroll
        for (int r = 0; r < 8; ++r) {
          const int off = (r + kh) * 720 + cbase;
          short8 bh = *(const short8*)(flh + off);
          short8 bm = *(const short8*)(flm + off);
          short8 bl = *(const short8*)(fll + off);
          acc[0][r] = MFMA16(ah0, bh, acc[0][r]);
          acc[0][r] = MFMA16(ah0, bm, acc[0][r]);
          acc[0][r] = MFMA16(am0, bh, acc[0][r]);
          acc[0][r] = MFMA16(ah0, bl, acc[0][r]);
          acc[0][r] = MFMA16(am0, bm, acc[0][r]);
          acc[0][r] = MFMA16(al0, bh, acc[0][r]);
          acc[1][r] = MFMA16(ah1, bh, acc[1][r]);
          acc[1][r] = MFMA16(ah1, bm, acc[1][r]);
          acc[1][r] = MFMA16(am1, bh, acc[1][r]);
          acc[1][r] = MFMA16(ah1, bl, acc[1][r]);
          acc[1][r] = MFMA16(am1, bm, acc[1][r]);
          acc[1][r] = MFMA16(al1, bh, acc[1][r]);
        }
      }
    }
    __builtin_amdgcn_s_setprio(0);
  }

  // ---- epilogue ----
  float bv[2][4];
#pragma unroll
  for (int ct = 0; ct < 2; ++ct)
#pragma unroll
    for (int i = 0; i < 4; ++i)
      bv[ct][i] = bias[cb * 128 + (wv * 2 + ct) * 16 + q * 4 + i];

  unsigned short* xlh = smem;           // [64 px][136 co-pad] u16
  unsigned short* xlm = smem + 8704;
  unsigned short* xll = smem + 17408;

  for (int hp = 0; hp < 2; ++hp) {
    __syncthreads();
#pragma unroll
    for (int ct = 0; ct < 2; ++ct) {
#pragma unroll
      for (int rr = 0; rr < 4; ++rr) {
        int r = hp * 4 + rr;
        unsigned short xh[4], xm[4], xl_[4];
#pragma unroll
        for (int i = 0; i < 4; ++i) {
          float xv = fmaxf(acc[ct][r][i] + bv[ct][i], 0.f);
          split3(xv, xh[i], xm[i], xl_[i]);
        }
        int px_l = rr * 16 + nl;
        int co_l = (wv * 2 + ct) * 16 + q * 4;
        uint2 ph, pm, pl;
        ph.x = xh[0] | (xh[1] << 16); ph.y = xh[2] | (xh[3] << 16);
        pm.x = xm[0] | (xm[1] << 16); pm.y = xm[2] | (xm[3] << 16);
        pl.x = xl_[0] | (xl_[1] << 16); pl.y = xl_[2] | (xl_[3] << 16);
        *(uint2*)(xlh + px_l * 136 + co_l) = ph;
        *(uint2*)(xlm + px_l * 136 + co_l) = pm;
        *(uint2*)(xll + px_l * 136 + co_l) = pl;
      }
    }
    __syncthreads();
    floatx4 ha[3];
#pragma unroll
    for (int mt = 0; mt < 3; ++mt) ha[mt] = (floatx4)0.f;
    for (int ks = 0; ks < 4; ++ks) {
      const int off = (wv * 16 + nl) * 136 + ks * 32 + q * 8;
      short8 bh = *(const short8*)(xlh + off);
      short8 bm = *(const short8*)(xlm + off);
      short8 bl = *(const short8*)(xll + off);
#pragma unroll
      for (int mt = 0; mt < 3; ++mt) {
        const int hb = (mt * 8 + cb * 4 + ks) * 64 + L;
        short8 hh = ((const short8*)HwF_h)[hb];
        short8 hm = ((const short8*)HwF_m)[hb];
        short8 hl = ((const short8*)HwF_l)[hb];
        ha[mt] = MFMA16(hh, bh, ha[mt]);
        ha[mt] = MFMA16(hh, bm, ha[mt]);
        ha[mt] = MFMA16(hm, bh, ha[mt]);
        ha[mt] = MFMA16(hh, bl, ha[mt]);
        ha[mt] = MFMA16(hm, bm, ha[mt]);
        ha[mt] = MFMA16(hl, bh, ha[mt]);
      }
    }
    int gr = h0 + hp * 4 + wv;
    int gc = w0 + nl;
    if (gc < FW) {
      float* lp = logits + ((size_t)cb * HW + (size_t)(gr * FW + gc)) * 45;
#pragma unroll
      for (int mt = 0; mt < 3; ++mt)
#pragma unroll
        for (int i = 0; i < 4; ++i) {
          int head = mt * 16 + q * 4 + i;
          if (head < 45) lp[head] = ha[mt][i];
        }
    }
  }
}

// =====================================================================
// finalize — sum cb partials + bias + anchors + deltas + sigmoid.
// Fused radix hist pass-0 AND scan-0 (last-block ticket).
// =====================================================================
__global__ __launch_bounds__(256) void finalize_kernel(
    const float* __restrict__ logits, const float* __restrict__ cls_b,
    const float* __restrict__ reg_b, float* __restrict__ prop,
    float* __restrict__ score, unsigned int* __restrict__ hist,
    unsigned int* __restrict__ state) {
  __shared__ unsigned int hsh[256], s1[256];
  __shared__ int lastb;
  int t = threadIdx.x;
  hsh[t] = 0u;
  __syncthreads();
  int px = blockIdx.x * 256 + t;
  if (px < HW) {
    float A[45];
    const float* lpA = logits + (size_t)px * 45;
    const float* lpB = logits + (size_t)HW * 45 + (size_t)px * 45;
#pragma unroll
    for (int i = 0; i < 45; ++i) A[i] = lpA[i] + lpB[i];
    const float scv[3] = {128.f, 256.f, 512.f};
    const float arv[3] = {0.5f, 1.f, 2.f};
    float sx = (float)(px % FW) * 8.0f;
    float sy = (float)(px / FW) * 8.0f;
#pragma unroll
    for (int a = 0; a < NUM_A; ++a) {
      int ai = a / 3, si = a % 3;
      float hr = sqrtf(arv[ai]);
      float wr = 1.0f / hr;
      float rw = nearbyintf(wr * scv[si] * 0.5f);
      float rh = nearbyintf(hr * scv[si] * 0.5f);
      float ax0 = sx - rw, ay0 = sy - rh, ax1 = sx + rw, ay1 = sy + rh;
      float aw = ax1 - ax0, ah = ay1 - ay0;
      float cx = ax0 + 0.5f * aw, cy = ay0 + 0.5f * ah;
      float dx = A[9 + a * 4 + 0] + reg_b[a * 4 + 0];
      float dy = A[9 + a * 4 + 1] + reg_b[a * 4 + 1];
      float dw = fminf(A[9 + a * 4 + 2] + reg_b[a * 4 + 2], BBOX_CLIP_F);
      float dh = fminf(A[9 + a * 4 + 3] + reg_b[a * 4 + 3], BBOX_CLIP_F);
      float pcx = dx * aw + cx;
      float pcy = dy * ah + cy;
      float pw = expf(dw) * aw;
      float ph = expf(dh) * ah;
      size_t base = (size_t)(px * NUM_A + a) * 4;
      prop[base + 0] = pcx - 0.5f * pw;
      prop[base + 1] = pcy - 0.5f * ph;
      prop[base + 2] = pcx + 0.5f * pw;
      prop[base + 3] = pcy + 0.5f * ph;
      float lg = A[a] + cls_b[a];
      float sv = 1.0f / (1.0f + expf(-lg));
      score[px * NUM_A + a] = sv;
      atomicAdd(&hsh[__float_as_uint(sv) >> 24], 1u);
    }
  }
  __syncthreads();
  if (hsh[t]) atomicAdd(&hist[t], hsh[t]);
  __syncthreads();
  if (t == 0) lastb = (atomicAdd(&state[8], 1u) == gridDim.x - 1u) ? 1 : 0;
  __syncthreads();
  if (!lastb) return;
  __threadfence();
  // ---- scan pass 0 ----
  unsigned int hv = hist[t];
  hist[t] = 0u;
  hsh[t] = hv;
  __syncthreads();
  unsigned int* A = hsh;
  unsigned int* B = s1;
  for (int off = 1; off < 256; off <<= 1) {
    B[t] = A[t] + ((t + off < 256) ? A[t + off] : 0u);
    __syncthreads();
    unsigned int* tmp = A; A = B; B = tmp;
  }
  unsigned int rem = (unsigned)PRE_K;
  unsigned int suf = A[t];
  unsigned int sufn = (t < 255) ? A[t + 1] : 0u;
  if (suf >= rem && sufn < rem) {
    state[0] = (unsigned int)t;
    state[1] = rem - sufn;
  }
}

// =====================================================================
// Radix passes 1..3: histogram + fused last-block scan (ticket).
// =====================================================================
__global__ __launch_bounds__(256) void hist_scan_kernel(
    const float* __restrict__ score, unsigned int* __restrict__ hist,
    unsigned int* __restrict__ state, unsigned int* __restrict__ ticket,
    int pass) {
  __shared__ unsigned int h[256], s1[256];
  __shared__ int lastb;
  int t = threadIdx.x;
  h[t] = 0;
  __syncthreads();
  unsigned int prefix = state[0];
  int shift = 24 - 8 * pass;
  for (int i = blockIdx.x * 256 + t; i < NANCH; i += gridDim.x * 256) {
    unsigned int key = __float_as_uint(score[i]);
    if ((key >> (32 - 8 * pass)) == prefix)
      atomicAdd(&h[(key >> shift) & 255u], 1u);
  }
  __syncthreads();
  if (h[t]) atomicAdd(&hist[t], h[t]);
  __syncthreads();
  if (t == 0) lastb = (atomicAdd(ticket, 1u) == gridDim.x - 1u) ? 1 : 0;
  __syncthreads();
  if (!lastb) return;
  __threadfence();
  unsigned int hv = hist[t];
  hist[t] = 0u;
  h[t] = hv;
  __syncthreads();
  unsigned int* A = h;
  unsigned int* B = s1;
  for (int off = 1; off < 256; off <<= 1) {
    B[t] = A[t] + ((t + off < 256) ? A[t + off] : 0u);
    __syncthreads();
    unsigned int* tmp = A; A = B; B = tmp;
  }
  unsigned int rem = state[1];
  unsigned int suf = A[t];
  unsigned int sufn = (t < 255) ? A[t + 1] : 0u;
  if (suf >= rem && sufn < rem) {
    state[0] = (prefix << 8) | (unsigned int)t;
    state[1] = rem - sufn;
  }
}

__global__ __launch_bounds__(256) void collect_kernel(
    const float* __restrict__ score, unsigned int* __restrict__ state,
    unsigned long long* __restrict__ cand) {
  unsigned int T = state[0];
  for (int i = blockIdx.x * 256 + threadIdx.x; i < NANCH; i += gridDim.x * 256) {
    unsigned int key = __float_as_uint(score[i]);
    if (key >= T) {
      unsigned int pos = atomicAdd(&state[4], 1u);
      if (pos < 4096u)
        cand[pos] = ((unsigned long long)key << 32) |
                    (unsigned long long)(~(unsigned int)i);
    }
  }
}

// =====================================================================
// Bitonic sort + gather + clip + valid + stable partition.
// ADAPTIVE sort size: cnt (keys >= exact top-2000 threshold) is almost
// always <= 2048; padding keys are 0 and only the first 2000 sorted
// entries are consumed, so sorting 2048 gives the identical result.
// Falls back to the full 4096 sort in the tie-heavy case.
// =====================================================================
__global__ __launch_bounds__(1024) void sort_gather(
    const unsigned long long* __restrict__ cand,
    const unsigned int* __restrict__ state, const float* __restrict__ prop,
    const float* __restrict__ score, float* __restrict__ boxes_s,
    float* __restrict__ sc_s) {
  __shared__ unsigned long long sk[4096];
  int t = threadIdx.x;
  unsigned int cnt = state[4];
  if (cnt > 4096u) cnt = 4096u;
  for (int e = t; e < 4096; e += 1024) sk[e] = (e < (int)cnt) ? cand[e] : 0ull;
  __syncthreads();
  const int n = (cnt <= 2048u) ? 2048 : 4096;
  for (int k = 2; k <= n; k <<= 1) {
    for (int j = k >> 1; j > 0; j >>= 1) {
      for (int i = t; i < n; i += 1024) {
        int l = i ^ j;
        if (l > i) {
          unsigned long long a = sk[i], bb = sk[l];
          bool up = ((i & k) == 0);
          bool sw = up ? (a < bb) : (a > bb);
          if (sw) { sk[i] = bb; sk[l] = a; }
        }
      }
      __syncthreads();
    }
  }
  float bx[2][4];
  float sc2[2] = {-1.f, -1.f};
  bool valid2[2] = {false, false};
#pragma unroll
  for (int s = 0; s < 2; ++s) {
    int i = t + s * 1024;
    bx[s][0] = bx[s][1] = bx[s][2] = bx[s][3] = 0.f;
    if (i < PRE_K) {
      unsigned long long v = sk[i];
      unsigned int idx = ~(unsigned int)(v & 0xFFFFFFFFull);
      float4 p = *(const float4*)(prop + (size_t)idx * 4);
      float x0 = fminf(fmaxf(p.x, 0.f), IMG_SZ);
      float y0 = fminf(fmaxf(p.y, 0.f), IMG_SZ);
      float x1 = fminf(fmaxf(p.z, 0.f), IMG_SZ);
      float y1 = fminf(fmaxf(p.w, 0.f), IMG_SZ);
      bool valid = (x1 - x0 >= MIN_SZ) && (y1 - y0 >= MIN_SZ);
      bx[s][0] = x0; bx[s][1] = y0; bx[s][2] = x1; bx[s][3] = y1;
      valid2[s] = valid;
      sc2[s] = valid ? score[idx] : -1.0f;
    }
  }
  __syncthreads();
  int* A = (int*)sk;
  int* B = A + 2048;
#pragma unroll
  for (int s = 0; s < 2; ++s) {
    int i = t + s * 1024;
    A[i] = (i < PRE_K && valid2[s]) ? 1 : 0;
  }
  __syncthreads();
  for (int off = 1; off < 2048; off <<= 1) {
#pragma unroll
    for (int s = 0; s < 2; ++s) {
      int i = t + s * 1024;
      B[i] = A[i] + ((i >= off) ? A[i - off] : 0);
    }
    __syncthreads();
    int* tmp = A; A = B; B = tmp;
  }
  int total = A[2047];
#pragma unroll
  for (int s = 0; s < 2; ++s) {
    int i = t + s * 1024;
    if (i < PRE_K) {
      int inc = A[i];
      int pos = valid2[s] ? (inc - 1) : (total + (i - inc));
      boxes_s[pos * 4 + 0] = bx[s][0];
      boxes_s[pos * 4 + 1] = bx[s][1];
      boxes_s[pos * 4 + 2] = bx[s][2];
      boxes_s[pos * 4 + 3] = bx[s][3];
      sc_s[pos] = sc2[s];
    }
  }
}

// =====================================================================
// IoU suppression bitmask (+ coalesced diag words).
// 256-thread blocks: wave wvi owns bj-tile blockIdx.x*4+wvi (grid 8x32)
// — same math as the 64-thread version, 4x fewer blocks.
// =====================================================================
__global__ __launch_bounds__(256) void iou_kernel(
    const float* __restrict__ boxes_s, unsigned long long* __restrict__ mask,
    unsigned long long* __restrict__ diag) {
  __shared__ float4 cbw[4][64];
  const int t = threadIdx.x;
  const int wvi = t >> 6, lane = t & 63;
  const int bj = blockIdx.x * 4 + wvi;
  const int bi = blockIdx.y;
  {
    int jc = bj * 64 + lane;
    float4 z; z.x = z.y = z.z = z.w = 0.f;
    cbw[wvi][lane] = (jc < PRE_K) ? *(const float4*)(boxes_s + (size_t)jc * 4) : z;
  }
  __syncthreads();
  int i = bi * 64 + lane;
  if (i >= PRE_K) return;
  float4 a = *(const float4*)(boxes_s + (size_t)i * 4);
  float areaA = (a.z - a.x) * (a.w - a.y);
  unsigned long long bits = 0ull;
  for (int jj = 0; jj < 64; ++jj) {
    int j = bj * 64 + jj;
    if (j < PRE_K && j > i) {
      float4 b = cbw[wvi][jj];
      float areaB = (b.z - b.x) * (b.w - b.y);
      float ltx = fmaxf(a.x, b.x), lty = fmaxf(a.y, b.y);
      float rbx = fminf(a.z, b.z), rby = fminf(a.w, b.w);
      float w = fmaxf(rbx - ltx, 0.f), h = fmaxf(rby - lty, 0.f);
      float inter = w * h;
      float iou = inter / (areaA + areaB - inter + 1e-9f);
      if (iou > NMS_TH) bits |= (1ull << jj);
    }
  }
  mask[(size_t)i * 32 + bj] = bits;
  if (bi == bj) diag[i] = bits;
}

// =====================================================================
// Block-resolved sequential NMS + final compaction to d_out.
// Push-apply: 8 rows/iter via SELECTS (register-only; rule #20).
// =====================================================================
__global__ __launch_bounds__(256) void nms_out_kernel(
    const float* __restrict__ boxes_s, const float* __restrict__ sc_s,
    const unsigned long long* __restrict__ mask,
    const unsigned long long* __restrict__ diag, float* __restrict__ out) {
  int t = threadIdx.x;
  for (int e = t; e < (OUT_K * 4 + OUT_K); e += 256) out[e] = 0.f;
  __shared__ unsigned long long keepw[32];
  if (t < 64) {
    unsigned long long removed = 0ull;  // lanes 0..31 own word t
    if (t < 32) {
      keepw[t] = 0ull;
#pragma unroll
      for (int k = 0; k < 64; ++k) {
        int idx = t * 64 + k;
        if (idx >= PRE_K || sc_s[idx] < 0.f) removed |= (1ull << k);
      }
    }
    const int w = t & 31;
    const int half = t >> 5;
    unsigned int kept = 0;
    for (int b = 0; b < 32; ++b) {
      unsigned long long d = diag[b * 64 + t];  // coalesced 512B
      unsigned long long dead = __shfl(removed, b);
      unsigned long long alive = 0ull;
#pragma unroll
      for (int k = 0; k < 64; ++k) {
        unsigned long long dk = __shfl(d, k);
        if (!((dead >> k) & 1ull)) {
          alive |= (1ull << k);
          dead |= dk;
        }
      }
      if (t == 0) keepw[b] = alive;
      kept += (unsigned)__popcll(alive);
      if (kept >= (unsigned)OUT_K || b == 31) break;
      // push-apply: OR alive rows' mask into future words; 8 rows/iter.
      unsigned long long am = alive;
      const long long rb = (long long)b * 64;
      while (am) {
        int k0 = __ffsll(am) - 1; am &= am - 1;
        int k1 = k0, k2 = k0, k3 = k0, k4 = k0, k5 = k0, k6 = k0, k7 = k0;
        if (am) { k1 = __ffsll(am) - 1; am &= am - 1; }
        if (am) { k2 = __ffsll(am) - 1; am &= am - 1; }
        if (am) { k3 = __ffsll(am) - 1; am &= am - 1; }
        if (am) { k4 = __ffsll(am) - 1; am &= am - 1; }
        if (am) { k5 = __ffsll(am) - 1; am &= am - 1; }
        if (am) { k6 = __ffsll(am) - 1; am &= am - 1; }
        if (am) { k7 = __ffsll(am) - 1; am &= am - 1; }
        unsigned long long v0 = mask[(size_t)(rb + (half ? k1 : k0)) * 32 + w];
        unsigned long long v1 = mask[(size_t)(rb + (half ? k3 : k2)) * 32 + w];
        unsigned long long v2 = mask[(size_t)(rb + (half ? k5 : k4)) * 32 + w];
        unsigned long long v3 = mask[(size_t)(rb + (half ? k7 : k6)) * 32 + w];
        unsigned long long vv = v0 | v1 | v2 | v3;
        unsigned long long hv = __shfl(vv, w + 32);
        if (t < 32) removed |= vv | hv;
      }
    }
  }
  __syncthreads();
  __shared__ unsigned int wbase[32];
  if (t == 0) {
    unsigned int s = 0;
    for (int k = 0; k < 32; ++k) {
      wbase[k] = s;
      s += (unsigned)__popcll(keepw[k]);
    }
  }
  __syncthreads();
  for (int i = t; i < PRE_K; i += 256) {
    unsigned long long w2 = keepw[i >> 6];
    if ((w2 >> (i & 63)) & 1ull) {
      unsigned int pos =
          wbase[i >> 6] +
          (unsigned)__popcll(w2 & ((1ull << (i & 63)) - 1ull));
      if (pos < OUT_K) {
        out[pos * 4 + 0] = boxes_s[i * 4 + 0];
        out[pos * 4 + 1] = boxes_s[i * 4 + 1];
        out[pos * 4 + 2] = boxes_s[i * 4 + 2];
        out[pos * 4 + 3] = boxes_s[i * 4 + 3];
        out[OUT_K * 4 + pos] = sc_s[i];
      }
    }
  }
}

// =====================================================================
extern "C" void kernel_launch(void* const* d_in, const int* in_sizes, int n_in,
                              void* d_out, int out_size, void* d_ws,
                              size_t ws_size, hipStream_t stream) {
  const float* feat = (const float*)d_in[1];
  const float* convw = (const float*)d_in[2];
  const float* convb = (const float*)d_in[3];
  const float* clsw = (const float*)d_in[4];
  const float* clsb = (const float*)d_in[5];
  const float* regw = (const float*)d_in[6];
  const float* regb = (const float*)d_in[7];

  char* ws = (char*)d_ws;
  unsigned int* hist = (unsigned int*)(ws + OFF_HIST);
  unsigned int* state = (unsigned int*)(ws + OFF_STATE);
  unsigned long long* cand = (unsigned long long*)(ws + OFF_CAND);
  float* boxes_s = (float*)(ws + OFF_BOXS);
  float* sc_s = (float*)(ws + OFF_SCS);
  unsigned long long* mask = (unsigned long long*)(ws + OFF_MASK);
  unsigned long long* diag = (unsigned long long*)(ws + OFF_DIAG);
  uint4* AW_h = (uint4*)(ws + OFF_AWH);
  uint4* AW_m = (uint4*)(ws + OFF_AWM);
  uint4* AW_l = (uint4*)(ws + OFF_AWL);
  uint4* HwF_h = (uint4*)(ws + OFF_HWH);
  uint4* HwF_m = (uint4*)(ws + OFF_HWM);
  uint4* HwF_l = (uint4*)(ws + OFF_HWL);
  float* logits = (float*)(ws + OFF_LOGIT);
  unsigned short* Ph = (unsigned short*)(ws + OFF_PH);
  unsigned short* Pm = (unsigned short*)(ws + OFF_PM);
  unsigned short* Pl = (unsigned short*)(ws + OFF_PL);
  float* prop = (float*)(ws + OFF_PROP);
  float* score = (float*)(ws + OFF_SCORE);
  float* out = (float*)d_out;

  // zero hist + state (incl. tickets state[8..11])
  hipMemsetAsync(ws, 0, OFF_STATE + 64, stream);

  prep_all<<<1550, 256, 0, stream>>>(feat, convw, clsw, regw, Ph, Pm, Pl,
                                     AW_h, AW_m, AW_l, HwF_h, HwF_m, HwF_l);
  conv_mfma<<<dim3(13, 25, 2), 256, 0, stream>>>(Ph, Pm, Pl, AW_h, AW_m, AW_l,
                                                 HwF_h, HwF_m, HwF_l, convb,
                                                 logits);
  finalize_kernel<<<157, 256, 0, stream>>>(logits, clsb, regb, prop, score,
                                           hist, state);
  for (int p = 1; p < 4; ++p)
    hist_scan_kernel<<<256, 256, 0, stream>>>(score, hist, state,
                                              &state[8 + p], p);
  collect_kernel<<<256, 256, 0, stream>>>(score, state, cand);
  sort_gather<<<1, 1024, 0, stream>>>(cand, state, prop, score, boxes_s, sc_s);
  iou_kernel<<<dim3(8, 32), 256, 0, stream>>>(boxes_s, mask, diag);
  nms_out_kernel<<<1, 256, 0, stream>>>(boxes_s, sc_s, mask, diag, out);
}

// Round 9
// 553.345 us; speedup vs baseline: 1.5264x; 1.0480x over previous
//
#include <hip/hip_runtime.h>
#include <math.h>

// ---------------- constants ----------------
#define FH 200
#define FW 200
#define HW 40000            // FH*FW
#define NUM_A 9
#define NANCH 360000        // HW*NUM_A
#define PRE_K 2000
#define OUT_K 1000
#define IMG_SZ 1600.0f
#define MIN_SZ 16.0f
#define NMS_TH 0.7f
#define BBOX_CLIP_F 4.135166556742356f   // log(1000/16)

// ---------------- workspace layout (bytes), total ~80.1 MB ----------------
// prop/score alias the PH plane region: planes are dead after conv_mfma,
// prop/score are written by finalize which runs after conv_mfma.
#define OFF_HIST   ((size_t)0)           // 256 u32 = 1024
#define OFF_STATE  ((size_t)1024)        // 16 u32 = 64 (incl tickets [8..11])
#define OFF_CAND   ((size_t)1088)        // 4096 u64 = 32768
#define OFF_BOXS   ((size_t)33856)       // 2000*4 f = 32000
#define OFF_SCS    ((size_t)65856)       // 2000 f = 8000
#define OFF_MASK   ((size_t)73856)       // 2000*32 u64 = 512000
#define OFF_DIAG   ((size_t)585856)      // 2048 u64 = 16384
#define OFF_AWH    ((size_t)602240)      // 73728*16 = 1179648
#define OFF_AWM    ((size_t)1781888)
#define OFF_AWL    ((size_t)2961536)
#define OFF_HWH    ((size_t)4141184)     // 1536*16 = 24576
#define OFF_HWM    ((size_t)4165760)
#define OFF_HWL    ((size_t)4190336)
#define OFF_LOGIT  ((size_t)4214912)     // 2 * 40000*45*4 = 14,400,000
#define OFF_PH     ((size_t)18614912)    // 8*40000*32*2 = 20,480,000
#define OFF_PM     ((size_t)39094912)
#define OFF_PL     ((size_t)59574912)    // end 80,054,912
#define OFF_PROP   ((size_t)18614912)    // alias PH (5,760,000)
#define OFF_SCORE  ((size_t)24374912)    // alias PH (1,440,000)

typedef __attribute__((ext_vector_type(8))) short short8;
typedef __attribute__((ext_vector_type(4))) float floatx4;
#define MFMA16(a, b, c) __builtin_amdgcn_mfma_f32_16x16x32_bf16(a, b, c, 0, 0, 0)

__device__ __forceinline__ unsigned short rne_bf16(float v) {
  unsigned int bb = __float_as_uint(v);
  return (unsigned short)((bb + 0x7FFFu + ((bb >> 16) & 1u)) >> 16);
}

// 3-way split: v = h + m + l + eps, |eps| <~ 2^-25 |v|
__device__ __forceinline__ void split3(float v, unsigned short& h,
                                       unsigned short& m, unsigned short& l) {
  h = rne_bf16(v);
  float r1 = v - __uint_as_float(((unsigned int)h) << 16);
  m = rne_bf16(r1);
  float r2 = r1 - __uint_as_float(((unsigned int)m) << 16);
  l = rne_bf16(r2);
}

// =====================================================================
// Fused prepass (one launch):
//   blocks [0,1256): split3 feat into 3 bf16 planes, layout [cib][px][32ci]
//   blocks [1256,1550): swizzle conv + head weights into MFMA A-fragment
//     order, 3-way split.
// =====================================================================
__global__ __launch_bounds__(256) void prep_all(
    const float* __restrict__ feat, const float* __restrict__ w,
    const float* __restrict__ cls_w, const float* __restrict__ reg_w,
    unsigned short* __restrict__ Ph, unsigned short* __restrict__ Pm,
    unsigned short* __restrict__ Pl, uint4* __restrict__ AW_h,
    uint4* __restrict__ AW_m, uint4* __restrict__ AW_l,
    uint4* __restrict__ HwF_h, uint4* __restrict__ HwF_m,
    uint4* __restrict__ HwF_l) {
  int bx = blockIdx.x;
  int t = threadIdx.x;
  if (bx < 1256) {
    int cib = bx & 7;
    int px = (bx >> 3) * 256 + t;
    if (px >= HW) return;
    unsigned short h[32], m[32], l[32];
#pragma unroll
    for (int ci = 0; ci < 32; ++ci)
      split3(feat[(size_t)(cib * 32 + ci) * HW + px], h[ci], m[ci], l[ci]);
    size_t base = ((size_t)cib * HW + px) * 32;
    uint4* dh = (uint4*)(Ph + base);
    uint4* dm = (uint4*)(Pm + base);
    uint4* dl = (uint4*)(Pl + base);
#pragma unroll
    for (int k = 0; k < 4; ++k) {
      uint4 vh, vm, vl;
      vh.x = h[k * 8 + 0] | (h[k * 8 + 1] << 16);
      vh.y = h[k * 8 + 2] | (h[k * 8 + 3] << 16);
      vh.z = h[k * 8 + 4] | (h[k * 8 + 5] << 16);
      vh.w = h[k * 8 + 6] | (h[k * 8 + 7] << 16);
      vm.x = m[k * 8 + 0] | (m[k * 8 + 1] << 16);
      vm.y = m[k * 8 + 2] | (m[k * 8 + 3] << 16);
      vm.z = m[k * 8 + 4] | (m[k * 8 + 5] << 16);
      vm.w = m[k * 8 + 6] | (m[k * 8 + 7] << 16);
      vl.x = l[k * 8 + 0] | (l[k * 8 + 1] << 16);
      vl.y = l[k * 8 + 2] | (l[k * 8 + 3] << 16);
      vl.z = l[k * 8 + 4] | (l[k * 8 + 5] << 16);
      vl.w = l[k * 8 + 6] | (l[k * 8 + 7] << 16);
      dh[k] = vh; dm[k] = vm; dl[k] = vl;
    }
    return;
  }
  int gid = (bx - 1256) * 256 + t;
  unsigned short h[8], m[8], l[8];
  if (gid < 73728) {
    int L = gid & 63;
    int idx = gid >> 6;            // (ctg*9+tap)*8 + cib
    int cib = idx & 7;
    int tmp = idx >> 3;
    int tap = tmp % 9;
    int ctg = tmp / 9;
    int co = ctg * 16 + (L & 15);
    int ci0 = cib * 32 + (L >> 4) * 8;
#pragma unroll
    for (int j = 0; j < 8; ++j)
      split3(w[(size_t)co * 2304 + (ci0 + j) * 9 + tap], h[j], m[j], l[j]);
    uint4 vh, vm, vl;
    vh.x = h[0] | (h[1] << 16); vh.y = h[2] | (h[3] << 16);
    vh.z = h[4] | (h[5] << 16); vh.w = h[6] | (h[7] << 16);
    vm.x = m[0] | (m[1] << 16); vm.y = m[2] | (m[3] << 16);
    vm.z = m[4] | (m[5] << 16); vm.w = m[6] | (m[7] << 16);
    vl.x = l[0] | (l[1] << 16); vl.y = l[2] | (l[3] << 16);
    vl.z = l[4] | (l[5] << 16); vl.w = l[6] | (l[7] << 16);
    AW_h[gid] = vh; AW_m[gid] = vm; AW_l[gid] = vl;
  } else if (gid < 73728 + 1536) {
    int g2 = gid - 73728;
    int L = g2 & 63;
    int idx = g2 >> 6;             // mt*8 + kb
    int kb = idx & 7;
    int mt = idx >> 3;
    int mm = mt * 16 + (L & 15);
    int co0 = kb * 32 + (L >> 4) * 8;
#pragma unroll
    for (int j = 0; j < 8; ++j) {
      float v = 0.f;
      if (mm < 9) v = cls_w[mm * 256 + co0 + j];
      else if (mm < 45) v = reg_w[(mm - 9) * 256 + co0 + j];
      split3(v, h[j], m[j], l[j]);
    }
    uint4 vh, vm, vl;
    vh.x = h[0] | (h[1] << 16); vh.y = h[2] | (h[3] << 16);
    vh.z = h[4] | (h[5] << 16); vh.w = h[6] | (h[7] << 16);
    vm.x = m[0] | (m[1] << 16); vm.y = m[2] | (m[3] << 16);
    vm.z = m[4] | (m[5] << 16); vm.w = m[6] | (m[7] << 16);
    vl.x = l[0] | (l[1] << 16); vl.y = l[2] | (l[3] << 16);
    vl.z = l[4] | (l[5] << 16); vl.w = l[6] | (l[7] << 16);
    HwF_h[g2] = vh; HwF_m[g2] = vm; HwF_l[g2] = vl;
  }
}

// =====================================================================
// Main conv+heads MFMA kernel — EXACT round-3/4 form (verified 233-239
// us, MfmaUtil ~57%, VGPR 76). Measured local optimum; conv untouched.
// =====================================================================
__global__ __launch_bounds__(256, 3) void conv_mfma(
    const unsigned short* __restrict__ Ph, const unsigned short* __restrict__ Pm,
    const unsigned short* __restrict__ Pl, const uint4* __restrict__ AW_h,
    const uint4* __restrict__ AW_m, const uint4* __restrict__ AW_l,
    const uint4* __restrict__ HwF_h, const uint4* __restrict__ HwF_m,
    const uint4* __restrict__ HwF_l, const float* __restrict__ bias,
    float* __restrict__ logits) {
  __shared__ alignas(16) unsigned short smem[26112];  // 52,224 B
  const int t = threadIdx.x;
  const int L = t & 63, wv = t >> 6;
  const int q = L >> 4, nl = L & 15;
  const int w0 = blockIdx.x * 16;
  const int h0 = blockIdx.y * 8;
  const int cb = blockIdx.z;

  floatx4 acc[2][8];
#pragma unroll
  for (int ct = 0; ct < 2; ++ct)
#pragma unroll
    for (int r = 0; r < 8; ++r) acc[ct][r] = (floatx4)0.f;

  unsigned short* flh = smem;            // [10 rows][18 cols][40 u16-pad]
  unsigned short* flm = smem + 7200;
  unsigned short* fll = smem + 14400;

  for (int cib = 0; cib < 8; ++cib) {
    __syncthreads();
#pragma unroll
    for (int j = 0; j < 9; ++j) {
      const int p = j / 3;               // plane (compile-time after unroll)
      const int c = (j % 3) * 256 + t;   // chunk id in [0,768)
      if (c < 720) {
        int rr = (int)((unsigned)c / 72u);
        int rem = c - rr * 72;
        int cc = rem >> 2, q16 = rem & 3;
        int gr = h0 - 1 + rr, gc = w0 - 1 + cc;
        uint4 v; v.x = v.y = v.z = v.w = 0u;
        if ((unsigned)gr < (unsigned)FH && (unsigned)gc < (unsigned)FW) {
          const unsigned short* pp = (p == 0) ? Ph : (p == 1) ? Pm : Pl;
          v = *(const uint4*)(pp +
                ((size_t)(cib * HW + gr * FW + gc) * 32 + q16 * 8));
        }
        *(uint4*)(smem + p * 7200 + rr * 720 + cc * 40 + q16 * 8) = v;
      }
    }
    __syncthreads();
    __builtin_amdgcn_s_setprio(1);
    const int ctg0 = cb * 8 + wv * 2;
    for (int kh = 0; kh < 3; ++kh) {
      for (int kw = 0; kw < 3; ++kw) {
        const int tap = kh * 3 + kw;
        const int abase = ((ctg0 * 9 + tap) * 8 + cib) * 64 + L;
        const int abase1 = abase + 9 * 8 * 64;
        short8 ah0 = ((const short8*)AW_h)[abase];
        short8 am0 = ((const short8*)AW_m)[abase];
        short8 al0 = ((const short8*)AW_l)[abase];
        short8 ah1 = ((const short8*)AW_h)[abase1];
        short8 am1 = ((const short8*)AW_m)[abase1];
        short8 al1 = ((const short8*)AW_l)[abase1];
        const int cbase = (nl + kw) * 40 + q * 8;
#pragma unroll
        for (int r = 0; r < 8; ++r) {
          const int off = (r + kh) * 720 + cbase;
          short8 bh = *(const short8*)(flh + off);
          short8 bm = *(const short8*)(flm + off);
          short8 bl = *(const short8*)(fll + off);
          acc[0][r] = MFMA16(ah0, bh, acc[0][r]);
          acc[0][r] = MFMA16(ah0, bm, acc[0][r]);
          acc[0][r] = MFMA16(am0, bh, acc[0][r]);
          acc[0][r] = MFMA16(ah0, bl, acc[0][r]);
          acc[0][r] = MFMA16(am0, bm, acc[0][r]);
          acc[0][r] = MFMA16(al0, bh, acc[0][r]);
          acc[1][r] = MFMA16(ah1, bh, acc[1][r]);
          acc[1][r] = MFMA16(ah1, bm, acc[1][r]);
          acc[1][r] = MFMA16(am1, bh, acc[1][r]);
          acc[1][r] = MFMA16(ah1, bl, acc[1][r]);
          acc[1][r] = MFMA16(am1, bm, acc[1][r]);
          acc[1][r] = MFMA16(al1, bh, acc[1][r]);
        }
      }
    }
    __builtin_amdgcn_s_setprio(0);
  }

  // ---- epilogue ----
  float bv[2][4];
#pragma unroll
  for (int ct = 0; ct < 2; ++ct)
#pragma unroll
    for (int i = 0; i < 4; ++i)
      bv[ct][i] = bias[cb * 128 + (wv * 2 + ct) * 16 + q * 4 + i];

  unsigned short* xlh = smem;           // [64 px][136 co-pad] u16
  unsigned short* xlm = smem + 8704;
  unsigned short* xll = smem + 17408;

  for (int hp = 0; hp < 2; ++hp) {
    __syncthreads();
#pragma unroll
    for (int ct = 0; ct < 2; ++ct) {
#pragma unroll
      for (int rr = 0; rr < 4; ++rr) {
        int r = hp * 4 + rr;
        unsigned short xh[4], xm[4], xl_[4];
#pragma unroll
        for (int i = 0; i < 4; ++i) {
          float xv = fmaxf(acc[ct][r][i] + bv[ct][i], 0.f);
          split3(xv, xh[i], xm[i], xl_[i]);
        }
        int px_l = rr * 16 + nl;
        int co_l = (wv * 2 + ct) * 16 + q * 4;
        uint2 ph, pm, pl;
        ph.x = xh[0] | (xh[1] << 16); ph.y = xh[2] | (xh[3] << 16);
        pm.x = xm[0] | (xm[1] << 16); pm.y = xm[2] | (xm[3] << 16);
        pl.x = xl_[0] | (xl_[1] << 16); pl.y = xl_[2] | (xl_[3] << 16);
        *(uint2*)(xlh + px_l * 136 + co_l) = ph;
        *(uint2*)(xlm + px_l * 136 + co_l) = pm;
        *(uint2*)(xll + px_l * 136 + co_l) = pl;
      }
    }
    __syncthreads();
    floatx4 ha[3];
#pragma unroll
    for (int mt = 0; mt < 3; ++mt) ha[mt] = (floatx4)0.f;
    for (int ks = 0; ks < 4; ++ks) {
      const int off = (wv * 16 + nl) * 136 + ks * 32 + q * 8;
      short8 bh = *(const short8*)(xlh + off);
      short8 bm = *(const short8*)(xlm + off);
      short8 bl = *(const short8*)(xll + off);
#pragma unroll
      for (int mt = 0; mt < 3; ++mt) {
        const int hb = (mt * 8 + cb * 4 + ks) * 64 + L;
        short8 hh = ((const short8*)HwF_h)[hb];
        short8 hm = ((const short8*)HwF_m)[hb];
        short8 hl = ((const short8*)HwF_l)[hb];
        ha[mt] = MFMA16(hh, bh, ha[mt]);
        ha[mt] = MFMA16(hh, bm, ha[mt]);
        ha[mt] = MFMA16(hm, bh, ha[mt]);
        ha[mt] = MFMA16(hh, bl, ha[mt]);
        ha[mt] = MFMA16(hm, bm, ha[mt]);
        ha[mt] = MFMA16(hl, bh, ha[mt]);
      }
    }
    int gr = h0 + hp * 4 + wv;
    int gc = w0 + nl;
    if (gc < FW) {
      float* lp = logits + ((size_t)cb * HW + (size_t)(gr * FW + gc)) * 45;
#pragma unroll
      for (int mt = 0; mt < 3; ++mt)
#pragma unroll
        for (int i = 0; i < 4; ++i) {
          int head = mt * 16 + q * 4 + i;
          if (head < 45) lp[head] = ha[mt][i];
        }
    }
  }
}

// =====================================================================
// finalize — sum cb partials + bias + anchors + deltas + sigmoid.
// Fused radix hist pass-0 AND scan-0 (last-block ticket).
// =====================================================================
__global__ __launch_bounds__(256) void finalize_kernel(
    const float* __restrict__ logits, const float* __restrict__ cls_b,
    const float* __restrict__ reg_b, float* __restrict__ prop,
    float* __restrict__ score, unsigned int* __restrict__ hist,
    unsigned int* __restrict__ state) {
  __shared__ unsigned int hsh[256], s1[256];
  __shared__ int lastb;
  int t = threadIdx.x;
  hsh[t] = 0u;
  __syncthreads();
  int px = blockIdx.x * 256 + t;
  if (px < HW) {
    float A[45];
    const float* lpA = logits + (size_t)px * 45;
    const float* lpB = logits + (size_t)HW * 45 + (size_t)px * 45;
#pragma unroll
    for (int i = 0; i < 45; ++i) A[i] = lpA[i] + lpB[i];
    const float scv[3] = {128.f, 256.f, 512.f};
    const float arv[3] = {0.5f, 1.f, 2.f};
    float sx = (float)(px % FW) * 8.0f;
    float sy = (float)(px / FW) * 8.0f;
#pragma unroll
    for (int a = 0; a < NUM_A; ++a) {
      int ai = a / 3, si = a % 3;
      float hr = sqrtf(arv[ai]);
      float wr = 1.0f / hr;
      float rw = nearbyintf(wr * scv[si] * 0.5f);
      float rh = nearbyintf(hr * scv[si] * 0.5f);
      float ax0 = sx - rw, ay0 = sy - rh, ax1 = sx + rw, ay1 = sy + rh;
      float aw = ax1 - ax0, ah = ay1 - ay0;
      float cx = ax0 + 0.5f * aw, cy = ay0 + 0.5f * ah;
      float dx = A[9 + a * 4 + 0] + reg_b[a * 4 + 0];
      float dy = A[9 + a * 4 + 1] + reg_b[a * 4 + 1];
      float dw = fminf(A[9 + a * 4 + 2] + reg_b[a * 4 + 2], BBOX_CLIP_F);
      float dh = fminf(A[9 + a * 4 + 3] + reg_b[a * 4 + 3], BBOX_CLIP_F);
      float pcx = dx * aw + cx;
      float pcy = dy * ah + cy;
      float pw = expf(dw) * aw;
      float ph = expf(dh) * ah;
      size_t base = (size_t)(px * NUM_A + a) * 4;
      prop[base + 0] = pcx - 0.5f * pw;
      prop[base + 1] = pcy - 0.5f * ph;
      prop[base + 2] = pcx + 0.5f * pw;
      prop[base + 3] = pcy + 0.5f * ph;
      float lg = A[a] + cls_b[a];
      float sv = 1.0f / (1.0f + expf(-lg));
      score[px * NUM_A + a] = sv;
      atomicAdd(&hsh[__float_as_uint(sv) >> 24], 1u);
    }
  }
  __syncthreads();
  if (hsh[t]) atomicAdd(&hist[t], hsh[t]);
  __syncthreads();
  if (t == 0) lastb = (atomicAdd(&state[8], 1u) == gridDim.x - 1u) ? 1 : 0;
  __syncthreads();
  if (!lastb) return;
  __threadfence();
  // ---- scan pass 0 ----
  unsigned int hv = hist[t];
  hist[t] = 0u;
  hsh[t] = hv;
  __syncthreads();
  unsigned int* A = hsh;
  unsigned int* B = s1;
  for (int off = 1; off < 256; off <<= 1) {
    B[t] = A[t] + ((t + off < 256) ? A[t + off] : 0u);
    __syncthreads();
    unsigned int* tmp = A; A = B; B = tmp;
  }
  unsigned int rem = (unsigned)PRE_K;
  unsigned int suf = A[t];
  unsigned int sufn = (t < 255) ? A[t + 1] : 0u;
  if (suf >= rem && sufn < rem) {
    state[0] = (unsigned int)t;
    state[1] = rem - sufn;
  }
}

// =====================================================================
// Radix passes 1..2: histogram + fused last-block scan (ticket).
// Pass 3 is DROPPED: selection runs on the 24-bit prefix; collect uses
// T = prefix24 << 8 (a lower bound on the exact threshold). All true
// top-2000 keys satisfy key >= T; the ~tens of extra candidates that
// share the 24-bit bin are eliminated by the exact bitonic sort, so the
// final output is identical. (4096-sort fallback still guards ties.)
// =====================================================================
__global__ __launch_bounds__(256) void hist_scan_kernel(
    const float* __restrict__ score, unsigned int* __restrict__ hist,
    unsigned int* __restrict__ state, unsigned int* __restrict__ ticket,
    int pass) {
  __shared__ unsigned int h[256], s1[256];
  __shared__ int lastb;
  int t = threadIdx.x;
  h[t] = 0;
  __syncthreads();
  unsigned int prefix = state[0];
  int shift = 24 - 8 * pass;
  for (int i = blockIdx.x * 256 + t; i < NANCH; i += gridDim.x * 256) {
    unsigned int key = __float_as_uint(score[i]);
    if ((key >> (32 - 8 * pass)) == prefix)
      atomicAdd(&h[(key >> shift) & 255u], 1u);
  }
  __syncthreads();
  if (h[t]) atomicAdd(&hist[t], h[t]);
  __syncthreads();
  if (t == 0) lastb = (atomicAdd(ticket, 1u) == gridDim.x - 1u) ? 1 : 0;
  __syncthreads();
  if (!lastb) return;
  __threadfence();
  unsigned int hv = hist[t];
  hist[t] = 0u;
  h[t] = hv;
  __syncthreads();
  unsigned int* A = h;
  unsigned int* B = s1;
  for (int off = 1; off < 256; off <<= 1) {
    B[t] = A[t] + ((t + off < 256) ? A[t + off] : 0u);
    __syncthreads();
    unsigned int* tmp = A; A = B; B = tmp;
  }
  unsigned int rem = state[1];
  unsigned int suf = A[t];
  unsigned int sufn = (t < 255) ? A[t + 1] : 0u;
  if (suf >= rem && sufn < rem) {
    state[0] = (prefix << 8) | (unsigned int)t;
    state[1] = rem - sufn;
  }
}

__global__ __launch_bounds__(256) void collect_kernel(
    const float* __restrict__ score, unsigned int* __restrict__ state,
    unsigned long long* __restrict__ cand) {
  unsigned int T = state[0] << 8;   // 24-bit prefix -> 32-bit lower bound
  for (int i = blockIdx.x * 256 + threadIdx.x; i < NANCH; i += gridDim.x * 256) {
    unsigned int key = __float_as_uint(score[i]);
    if (key >= T) {
      unsigned int pos = atomicAdd(&state[4], 1u);
      if (pos < 4096u)
        cand[pos] = ((unsigned long long)key << 32) |
                    (unsigned long long)(~(unsigned int)i);
    }
  }
}

// =====================================================================
// Bitonic sort + gather + clip + valid + stable partition.
// ADAPTIVE sort size (2048 when cnt fits; full 4096 fallback for ties).
// =====================================================================
__global__ __launch_bounds__(1024) void sort_gather(
    const unsigned long long* __restrict__ cand,
    const unsigned int* __restrict__ state, const float* __restrict__ prop,
    const float* __restrict__ score, float* __restrict__ boxes_s,
    float* __restrict__ sc_s) {
  __shared__ unsigned long long sk[4096];
  int t = threadIdx.x;
  unsigned int cnt = state[4];
  if (cnt > 4096u) cnt = 4096u;
  for (int e = t; e < 4096; e += 1024) sk[e] = (e < (int)cnt) ? cand[e] : 0ull;
  __syncthreads();
  const int n = (cnt <= 2048u) ? 2048 : 4096;
  for (int k = 2; k <= n; k <<= 1) {
    for (int j = k >> 1; j > 0; j >>= 1) {
      for (int i = t; i < n; i += 1024) {
        int l = i ^ j;
        if (l > i) {
          unsigned long long a = sk[i], bb = sk[l];
          bool up = ((i & k) == 0);
          bool sw = up ? (a < bb) : (a > bb);
          if (sw) { sk[i] = bb; sk[l] = a; }
        }
      }
      __syncthreads();
    }
  }
  float bx[2][4];
  float sc2[2] = {-1.f, -1.f};
  bool valid2[2] = {false, false};
#pragma unroll
  for (int s = 0; s < 2; ++s) {
    int i = t + s * 1024;
    bx[s][0] = bx[s][1] = bx[s][2] = bx[s][3] = 0.f;
    if (i < PRE_K) {
      unsigned long long v = sk[i];
      unsigned int idx = ~(unsigned int)(v & 0xFFFFFFFFull);
      float4 p = *(const float4*)(prop + (size_t)idx * 4);
      float x0 = fminf(fmaxf(p.x, 0.f), IMG_SZ);
      float y0 = fminf(fmaxf(p.y, 0.f), IMG_SZ);
      float x1 = fminf(fmaxf(p.z, 0.f), IMG_SZ);
      float y1 = fminf(fmaxf(p.w, 0.f), IMG_SZ);
      bool valid = (x1 - x0 >= MIN_SZ) && (y1 - y0 >= MIN_SZ);
      bx[s][0] = x0; bx[s][1] = y0; bx[s][2] = x1; bx[s][3] = y1;
      valid2[s] = valid;
      sc2[s] = valid ? score[idx] : -1.0f;
    }
  }
  __syncthreads();
  int* A = (int*)sk;
  int* B = A + 2048;
#pragma unroll
  for (int s = 0; s < 2; ++s) {
    int i = t + s * 1024;
    A[i] = (i < PRE_K && valid2[s]) ? 1 : 0;
  }
  __syncthreads();
  for (int off = 1; off < 2048; off <<= 1) {
#pragma unroll
    for (int s = 0; s < 2; ++s) {
      int i = t + s * 1024;
      B[i] = A[i] + ((i >= off) ? A[i - off] : 0);
    }
    __syncthreads();
    int* tmp = A; A = B; B = tmp;
  }
  int total = A[2047];
#pragma unroll
  for (int s = 0; s < 2; ++s) {
    int i = t + s * 1024;
    if (i < PRE_K) {
      int inc = A[i];
      int pos = valid2[s] ? (inc - 1) : (total + (i - inc));
      boxes_s[pos * 4 + 0] = bx[s][0];
      boxes_s[pos * 4 + 1] = bx[s][1];
      boxes_s[pos * 4 + 2] = bx[s][2];
      boxes_s[pos * 4 + 3] = bx[s][3];
      sc_s[pos] = sc2[s];
    }
  }
}

// =====================================================================
// IoU suppression bitmask (+ coalesced diag words).
// 256-thread blocks: wave wvi owns bj-tile blockIdx.x*4+wvi (grid 8x32).
// =====================================================================
__global__ __launch_bounds__(256) void iou_kernel(
    const float* __restrict__ boxes_s, unsigned long long* __restrict__ mask,
    unsigned long long* __restrict__ diag) {
  __shared__ float4 cbw[4][64];
  const int t = threadIdx.x;
  const int wvi = t >> 6, lane = t & 63;
  const int bj = blockIdx.x * 4 + wvi;
  const int bi = blockIdx.y;
  {
    int jc = bj * 64 + lane;
    float4 z; z.x = z.y = z.z = z.w = 0.f;
    cbw[wvi][lane] = (jc < PRE_K) ? *(const float4*)(boxes_s + (size_t)jc * 4) : z;
  }
  __syncthreads();
  int i = bi * 64 + lane;
  if (i >= PRE_K) return;
  float4 a = *(const float4*)(boxes_s + (size_t)i * 4);
  float areaA = (a.z - a.x) * (a.w - a.y);
  unsigned long long bits = 0ull;
  for (int jj = 0; jj < 64; ++jj) {
    int j = bj * 64 + jj;
    if (j < PRE_K && j > i) {
      float4 b = cbw[wvi][jj];
      float areaB = (b.z - b.x) * (b.w - b.y);
      float ltx = fmaxf(a.x, b.x), lty = fmaxf(a.y, b.y);
      float rbx = fminf(a.z, b.z), rby = fminf(a.w, b.w);
      float w = fmaxf(rbx - ltx, 0.f), h = fmaxf(rby - lty, 0.f);
      float inter = w * h;
      float iou = inter / (areaA + areaB - inter + 1e-9f);
      if (iou > NMS_TH) bits |= (1ull << jj);
    }
  }
  mask[(size_t)i * 32 + bj] = bits;
  if (bi == bj) diag[i] = bits;
}

// =====================================================================
// Block-resolved sequential NMS + final compaction to d_out.
// Push-apply: 16 rows/iter via NAMED scalars + selects (register-only —
// R4's 16-row kk[16] array was runtime-indexed -> scratch, rule #20;
// named k0..k15 with (half ? kOdd : kEven) selects stays in VGPRs).
// 8 independent mask loads per lane per iteration halves the
// latency-serial iteration count vs the 8-row form. Same OR-set.
// =====================================================================
__global__ __launch_bounds__(256) void nms_out_kernel(
    const float* __restrict__ boxes_s, const float* __restrict__ sc_s,
    const unsigned long long* __restrict__ mask,
    const unsigned long long* __restrict__ diag, float* __restrict__ out) {
  int t = threadIdx.x;
  for (int e = t; e < (OUT_K * 4 + OUT_K); e += 256) out[e] = 0.f;
  __shared__ unsigned long long keepw[32];
  if (t < 64) {
    unsigned long long removed = 0ull;  // lanes 0..31 own word t
    if (t < 32) {
      keepw[t] = 0ull;
#pragma unroll
      for (int k = 0; k < 64; ++k) {
        int idx = t * 64 + k;
        if (idx >= PRE_K || sc_s[idx] < 0.f) removed |= (1ull << k);
      }
    }
    const int w = t & 31;
    const int half = t >> 5;
    unsigned int kept = 0;
    for (int b = 0; b < 32; ++b) {
      unsigned long long d = diag[b * 64 + t];  // coalesced 512B
      unsigned long long dead = __shfl(removed, b);
      unsigned long long alive = 0ull;
#pragma unroll
      for (int k = 0; k < 64; ++k) {
        unsigned long long dk = __shfl(d, k);
        if (!((dead >> k) & 1ull)) {
          alive |= (1ull << k);
          dead |= dk;
        }
      }
      if (t == 0) keepw[b] = alive;
      kept += (unsigned)__popcll(alive);
      if (kept >= (unsigned)OUT_K || b == 31) break;
      // push-apply: OR alive rows' mask into future words; 16 rows/iter.
      unsigned long long am = alive;
      const long long rb = (long long)b * 64;
      while (am) {
        int k0 = __ffsll(am) - 1; am &= am - 1;
        int k1 = k0, k2 = k0, k3 = k0, k4 = k0, k5 = k0, k6 = k0, k7 = k0;
        int k8 = k0, k9 = k0, k10 = k0, k11 = k0, k12 = k0, k13 = k0;
        int k14 = k0, k15 = k0;
        if (am) { k1 = __ffsll(am) - 1; am &= am - 1; }
        if (am) { k2 = __ffsll(am) - 1; am &= am - 1; }
        if (am) { k3 = __ffsll(am) - 1; am &= am - 1; }
        if (am) { k4 = __ffsll(am) - 1; am &= am - 1; }
        if (am) { k5 = __ffsll(am) - 1; am &= am - 1; }
        if (am) { k6 = __ffsll(am) - 1; am &= am - 1; }
        if (am) { k7 = __ffsll(am) - 1; am &= am - 1; }
        if (am) { k8 = __ffsll(am) - 1; am &= am - 1; }
        if (am) { k9 = __ffsll(am) - 1; am &= am - 1; }
        if (am) { k10 = __ffsll(am) - 1; am &= am - 1; }
        if (am) { k11 = __ffsll(am) - 1; am &= am - 1; }
        if (am) { k12 = __ffsll(am) - 1; am &= am - 1; }
        if (am) { k13 = __ffsll(am) - 1; am &= am - 1; }
        if (am) { k14 = __ffsll(am) - 1; am &= am - 1; }
        if (am) { k15 = __ffsll(am) - 1; am &= am - 1; }
        unsigned long long v0 = mask[(size_t)(rb + (half ? k1 : k0)) * 32 + w];
        unsigned long long v1 = mask[(size_t)(rb + (half ? k3 : k2)) * 32 + w];
        unsigned long long v2 = mask[(size_t)(rb + (half ? k5 : k4)) * 32 + w];
        unsigned long long v3 = mask[(size_t)(rb + (half ? k7 : k6)) * 32 + w];
        unsigned long long v4 = mask[(size_t)(rb + (half ? k9 : k8)) * 32 + w];
        unsigned long long v5 = mask[(size_t)(rb + (half ? k11 : k10)) * 32 + w];
        unsigned long long v6 = mask[(size_t)(rb + (half ? k13 : k12)) * 32 + w];
        unsigned long long v7 = mask[(size_t)(rb + (half ? k15 : k14)) * 32 + w];
        unsigned long long vv = v0 | v1 | v2 | v3 | v4 | v5 | v6 | v7;
        unsigned long long hv = __shfl(vv, w + 32);
        if (t < 32) removed |= vv | hv;
      }
    }
  }
  __syncthreads();
  __shared__ unsigned int wbase[32];
  if (t == 0) {
    unsigned int s = 0;
    for (int k = 0; k < 32; ++k) {
      wbase[k] = s;
      s += (unsigned)__popcll(keepw[k]);
    }
  }
  __syncthreads();
  for (int i = t; i < PRE_K; i += 256) {
    unsigned long long w2 = keepw[i >> 6];
    if ((w2 >> (i & 63)) & 1ull) {
      unsigned int pos =
          wbase[i >> 6] +
          (unsigned)__popcll(w2 & ((1ull << (i & 63)) - 1ull));
      if (pos < OUT_K) {
        out[pos * 4 + 0] = boxes_s[i * 4 + 0];
        out[pos * 4 + 1] = boxes_s[i * 4 + 1];
        out[pos * 4 + 2] = boxes_s[i * 4 + 2];
        out[pos * 4 + 3] = boxes_s[i * 4 + 3];
        out[OUT_K * 4 + pos] = sc_s[i];
      }
    }
  }
}

// =====================================================================
extern "C" void kernel_launch(void* const* d_in, const int* in_sizes, int n_in,
                              void* d_out, int out_size, void* d_ws,
                              size_t ws_size, hipStream_t stream) {
  const float* feat = (const float*)d_in[1];
  const float* convw = (const float*)d_in[2];
  const float* convb = (const float*)d_in[3];
  const float* clsw = (const float*)d_in[4];
  const float* clsb = (const float*)d_in[5];
  const float* regw = (const float*)d_in[6];
  const float* regb = (const float*)d_in[7];

  char* ws = (char*)d_ws;
  unsigned int* hist = (unsigned int*)(ws + OFF_HIST);
  unsigned int* state = (unsigned int*)(ws + OFF_STATE);
  unsigned long long* cand = (unsigned long long*)(ws + OFF_CAND);
  float* boxes_s = (float*)(ws + OFF_BOXS);
  float* sc_s = (float*)(ws + OFF_SCS);
  unsigned long long* mask = (unsigned long long*)(ws + OFF_MASK);
  unsigned long long* diag = (unsigned long long*)(ws + OFF_DIAG);
  uint4* AW_h = (uint4*)(ws + OFF_AWH);
  uint4* AW_m = (uint4*)(ws + OFF_AWM);
  uint4* AW_l = (uint4*)(ws + OFF_AWL);
  uint4* HwF_h = (uint4*)(ws + OFF_HWH);
  uint4* HwF_m = (uint4*)(ws + OFF_HWM);
  uint4* HwF_l = (uint4*)(ws + OFF_HWL);
  float* logits = (float*)(ws + OFF_LOGIT);
  unsigned short* Ph = (unsigned short*)(ws + OFF_PH);
  unsigned short* Pm = (unsigned short*)(ws + OFF_PM);
  unsigned short* Pl = (unsigned short*)(ws + OFF_PL);
  float* prop = (float*)(ws + OFF_PROP);
  float* score = (float*)(ws + OFF_SCORE);
  float* out = (float*)d_out;

  // zero hist + state (incl. tickets state[8..11])
  hipMemsetAsync(ws, 0, OFF_STATE + 64, stream);

  prep_all<<<1550, 256, 0, stream>>>(feat, convw, clsw, regw, Ph, Pm, Pl,
                                     AW_h, AW_m, AW_l, HwF_h, HwF_m, HwF_l);
  conv_mfma<<<dim3(13, 25, 2), 256, 0, stream>>>(Ph, Pm, Pl, AW_h, AW_m, AW_l,
                                                 HwF_h, HwF_m, HwF_l, convb,
                                                 logits);
  finalize_kernel<<<157, 256, 0, stream>>>(logits, clsb, regb, prop, score,
                                           hist, state);
  for (int p = 1; p < 3; ++p)
    hist_scan_kernel<<<256, 256, 0, stream>>>(score, hist, state,
                                              &state[8 + p], p);
  collect_kernel<<<256, 256, 0, stream>>>(score, state, cand);
  sort_gather<<<1, 1024, 0, stream>>>(cand, state, prop, score, boxes_s, sc_s);
  iou_kernel<<<dim3(8, 32), 256, 0, stream>>>(boxes_s, mask, diag);
  nms_out_kernel<<<1, 256, 0, stream>>>(boxes_s, sc_s, mask, diag, out);
}